// Round 6
// baseline (1300.469 us; speedup 1.0000x reference)
//
#include <hip/hip_runtime.h>
#include <stdint.h>

#define HID    2048
#define MPTS   16425
#define MTILES 129    // ceil(16425/128)
#define NTIL   16     // 2048/128
#define KTIL   64     // 2048/32
#define BIMG   5120   // f16 elems per packed padded B tile image (128 rows * 40)
#define BSLOT  6144   // f16 elems per LDS ring slot (12 KB; 12 x 1KB chunks)

typedef float    f32x4 __attribute__((ext_vector_type(4)));
typedef _Float16 f16x8 __attribute__((ext_vector_type(8)));

// P-layout (A-operand fragment order) for activations:
// elem(row, k) -> linear ((tile*64+kt)<<12) + rowgrp*512 + quad*128 + lidx*8 + j
//   tile=row>>7, rowgrp=(row>>4)&7, lidx=row&15, kt=k>>5, quad=(k>>3)&3, j=k&7
// Consumer wave A-frag load = base + lane*8 halves (1KB fully coalesced).

// ---------------------------------------------------------------------------
// Pack fp32 W (K x N row-major) into single-fp16 padded tile images:
// img(L,nt,kt)[n*40+k] = (f16)W[kt*32+k][nt*128+n]; pad k=32..39 zeros.
// ---------------------------------------------------------------------------
__global__ void pack_w16(const float* __restrict__ w1,
                         const float* __restrict__ w2,
                         const float* __restrict__ w3,
                         _Float16* __restrict__ wp) {
    const int kt = blockIdx.x, nt = blockIdx.y, L = blockIdx.z;
    const float* W = (L == 0) ? w1 : ((L == 1) ? w2 : w3);
    __shared__ float tl[128 * 33];   // [n][k] transposed, padded
    const int tid = threadIdx.x;
    const int k  = tid >> 3;          // 0..31
    const int nc = (tid & 7) * 16;    // 0..112
    const float* src = W + (size_t)(kt * 32 + k) * HID + nt * 128 + nc;
    #pragma unroll
    for (int j = 0; j < 16; ++j) tl[(nc + j) * 33 + k] = src[j];
    __syncthreads();
    const size_t base = (size_t)(L * 1024 + nt * 64 + kt) * BIMG;
    for (int e = tid; e < BIMG; e += 256) {
        int n = e / 40, kk = e - n * 40;
        wp[base + e] = (kk < 32) ? (_Float16)tl[n * 33 + kk] : (_Float16)0.f;
    }
}

// ---------------------------------------------------------------------------
// Layer 0: v=relu(xs*w0+b0); store fp16 hi/lo pair in P-layout
// ---------------------------------------------------------------------------
__global__ void layer0p(const float* __restrict__ xs,
                        const float* __restrict__ w0,
                        const float* __restrict__ b0,
                        _Float16* __restrict__ Ahg,
                        _Float16* __restrict__ Alg, int row0) {
    const int r = blockIdx.x;             // chunk-local row
    const int grow = row0 + r;
    const int j0 = threadIdx.x * 8;       // k
    const float x = (grow < MPTS) ? xs[grow] : 0.f;
    f16x8 h, l;
    #pragma unroll
    for (int q = 0; q < 8; ++q) {
        float v = x * w0[j0 + q] + b0[j0 + q];
        v = v > 0.f ? v : 0.f;
        _Float16 hs = (_Float16)v;
        h[q] = hs;
        l[q] = (_Float16)(v - (float)hs);
    }
    const int t = r >> 7, rowgrp = (r >> 4) & 7, lidx = r & 15;
    const int kt = j0 >> 5, quad = (j0 >> 3) & 3;
    const size_t dst = ((size_t)(t * 64 + kt) << 12) + rowgrp * 512 + quad * 128 + lidx * 8;
    *(f16x8*)(Ahg + dst) = h;
    *(f16x8*)(Alg + dst) = l;
}

// ---------------------------------------------------------------------------
// MFMA GEMM v11 (fp16): counted-vmcnt ring (T3+T4) + setprio (T5).
// Rounds 3/5 falsified barrier-count and occupancy theories; the shared
// stall is the __syncthreads vmcnt(0) drain (same-superstep prefetch must
// complete its HBM/L2 round trip before ANY wave proceeds). v11 removes
// every drain from the main loop:
//   - 4-slot LDS image ring (12 KB slots), prefetch distance 3 kt.
//   - per-wave vmem is made exactly countable: 12 uniform PF chunks/image
//     (3 per wave) + 8 A-loads per kt = 11 ops/body.
//   - gate per kt: s_waitcnt vmcnt(22) (own PF(kt), issued 3 bodies ago,
//     retired; 2 younger bodies = 22 ops stay IN FLIGHT) + raw s_barrier.
//   - A(kt+1) issued BEFORE PF(kt+3): the compiler's A-wait then resolves
//     at vmcnt(14) without draining younger prefetches (round-1's bug).
//   - s_setprio(1) around the MFMA cluster (T5; pays only with phase
//     role-split, which this schedule now has).
// Accumulation order identical to v7-v10 -> absmax unchanged.
// LDS 4 x 12 KB = 48 KB; (256,3) -> 144 KB/CU, VGPR headroom proven in r3.
// ---------------------------------------------------------------------------
__launch_bounds__(256, 3)
__global__ void gemm_hl(const _Float16* __restrict__ Ahg,
                        const _Float16* __restrict__ Alg,
                        const _Float16* __restrict__ wp,
                        const float* __restrict__ bias,
                        _Float16* __restrict__ Chg,
                        _Float16* __restrict__ Clg,
                        int layer, int write_lo) {
    __shared__ _Float16 Bs[4][BSLOT];   // 4 x 12288 B = 48 KB ring

    const int tid  = threadIdx.x;
    const int lane = tid & 63;
    const int wave = tid >> 6;
    const int quad = lane >> 4;
    const int lidx = lane & 15;

    // T1: bijective XCD-chunked swizzle (nwg = 16*tiles, always % 8 == 0).
    const int nwg = (int)(gridDim.x * gridDim.y);
    const int L   = (int)(blockIdx.y * gridDim.x + blockIdx.x);
    const int F   = (L & 7) * (nwg >> 3) + (L >> 3);
    const int nt  = F & 15;             // gridDim.x == NTIL == 16
    const int mt  = F >> 4;             // chunk-local tile

    const int mbase = (wave >> 1) * 64;
    const int nbase = (wave & 1) * 64;

    const char* gW = (const char*)(wp + (size_t)(layer * 1024 + nt * 64) * BIMG);

    const size_t abase = ((size_t)(mt * 64) << 12) + (size_t)(mbase >> 4) * 512 + (size_t)lane * 8;
    const _Float16* aH = Ahg + abase;
    const _Float16* aL = Alg + abase;

    f32x4 acc[4][4];
    #pragma unroll
    for (int i = 0; i < 4; ++i)
        #pragma unroll
        for (int j = 0; j < 4; ++j) acc[i][j] = (f32x4)0.f;

// 12 uniform 1KB chunks per image (chunks 10,11 read the next image's head:
// harmless garbage into the unread LDS slot tail; wp is tail-padded 4 KB).
#define PF_B(KT, BUF) do {                                                            \
    const char* nW_ = gW + (size_t)(KT) * (BIMG * 2);                                 \
    char* dW_ = (char*)&Bs[BUF][0];                                                   \
    const int t0_ = wave * 3;                                                         \
    _Pragma("unroll")                                                                 \
    for (int c_ = 0; c_ < 3; ++c_) {                                                  \
        __builtin_amdgcn_global_load_lds(                                             \
            (const __attribute__((address_space(1))) unsigned int*)(nW_ + (t0_ + c_) * 1024 + lane * 16), \
            (__attribute__((address_space(3))) unsigned int*)(dW_ + (t0_ + c_) * 1024), 16, 0, 0); \
    }                                                                                 \
} while (0)

#define LD_A(KT, H, Lo) do {                                                          \
    const size_t ak_ = (size_t)(KT) << 12;                                            \
    _Pragma("unroll")                                                                 \
    for (int mm = 0; mm < 4; ++mm) {                                                  \
        H[mm]  = *(const f16x8*)(aH + ak_ + mm * 512);                                \
        Lo[mm] = *(const f16x8*)(aL + ak_ + mm * 512);                                \
    }                                                                                 \
} while (0)

#define LD_B(BUF, BF) do {                                                            \
    _Pragma("unroll")                                                                 \
    for (int nn = 0; nn < 4; ++nn) {                                                  \
        int r_ = nbase + nn * 16 + lidx;                                              \
        BF[nn] = *(const f16x8*)(&Bs[BUF][r_ * 40 + quad * 8]);                       \
    }                                                                                 \
} while (0)

#define MFMA32(AH, AL, BF) do {                                                       \
    _Pragma("unroll")                                                                 \
    for (int mm = 0; mm < 4; ++mm)                                                    \
        _Pragma("unroll")                                                             \
        for (int nn = 0; nn < 4; ++nn) {                                              \
            acc[mm][nn] = __builtin_amdgcn_mfma_f32_16x16x32_f16(AH[mm], BF[nn], acc[mm][nn], 0, 0, 0); \
            acc[mm][nn] = __builtin_amdgcn_mfma_f32_16x16x32_f16(AL[mm], BF[nn], acc[mm][nn], 0, 0, 0); \
        }                                                                             \
} while (0)

// Counted gate: own PF(kt) retired, younger prefetches stay in flight.
#define GATE(N) do {                                                                  \
    asm volatile("s_waitcnt vmcnt(%0)" :: "n"(N));                                    \
    __builtin_amdgcn_sched_barrier(0);                                                \
    __builtin_amdgcn_s_barrier();                                                     \
    __builtin_amdgcn_sched_barrier(0);                                                \
} while (0)

// BODY(kt): gate -> ds_read B[kt] -> issue A(kt+1) -> issue PF(kt+3) -> MFMA.
#define BODY(KT, BUF, GN, DO_PF, DO_A, CH, CL, NH, NL) do {                           \
    GATE(GN);                                                                         \
    f16x8 bfr_[4];                                                                    \
    LD_B(BUF, bfr_);                                                                  \
    if (DO_A)  LD_A((KT) + 1, NH, NL);                                                \
    if (DO_PF) PF_B((KT) + 3, ((KT) + 3) & 3);                                        \
    __builtin_amdgcn_s_setprio(1);                                                    \
    MFMA32(CH, CL, bfr_);                                                             \
    __builtin_amdgcn_s_setprio(0);                                                    \
} while (0)

    f16x8 cah[4], cal[4], nah[4], nal[4];

    // prologue: A(0) first (8), then PF images 0,1,2 (3 each).
    LD_A(0, cah, cal);
    PF_B(0, 0);
    PF_B(1, 1);
    PF_B(2, 2);

    // gates: kt0: PF(0)+6 younger; kt1: PF(1)+14; kt>=2 steady: +22.
    BODY(0, 0,  6, 1, 1, cah, cal, nah, nal);
    BODY(1, 1, 14, 1, 1, nah, nal, cah, cal);
    BODY(2, 2, 22, 1, 1, cah, cal, nah, nal);
    BODY(3, 3, 22, 1, 1, nah, nal, cah, cal);
    for (int k4 = 1; k4 < 15; ++k4) {   // kt = 4..59
        BODY(4 * k4 + 0, 0, 22, 1, 1, cah, cal, nah, nal);
        BODY(4 * k4 + 1, 1, 22, 1, 1, nah, nal, cah, cal);
        BODY(4 * k4 + 2, 2, 22, 1, 1, cah, cal, nah, nal);
        BODY(4 * k4 + 3, 3, 22, 1, 1, nah, nal, cah, cal);
    }
    BODY(60, 0, 22, 1, 1, cah, cal, nah, nal);   // last PF (image 63)
    BODY(61, 1, 22, 0, 1, nah, nal, cah, cal);   // after: b59(11)+b60(11)
    BODY(62, 2, 19, 0, 1, cah, cal, nah, nal);   // after: b60(11)+b61(8)
    BODY(63, 3, 16, 0, 0, nah, nal, cah, cal);   // after: b61(8)+b62(8)

#undef BODY
#undef GATE
#undef MFMA32
#undef LD_B
#undef LD_A
#undef PF_B

    // epilogue: C/D layout col=lane&15, row=quad*4+reg; write P-layout pair
    #pragma unroll
    for (int nn = 0; nn < 4; ++nn) {
        const int col = nt * 128 + nbase + nn * 16 + lidx;   // k of next layer
        const float bv = bias[col];
        const int kt2 = col >> 5, quad2 = (col >> 3) & 3, j2 = col & 7;
        const size_t cb = ((size_t)(mt * 64 + kt2) << 12) + quad2 * 128 + j2;
        #pragma unroll
        for (int mm = 0; mm < 4; ++mm) {
            const int rowg = (mbase >> 4) + mm;             // rowgrp
            #pragma unroll
            for (int r = 0; r < 4; ++r) {
                const int lidx2 = quad * 4 + r;             // row & 15
                float v = acc[mm][nn][r] + bv;
                v = v > 0.f ? v : 0.f;
                _Float16 hs = (_Float16)v;
                const size_t idx = cb + rowg * 512 + lidx2 * 8;
                Chg[idx] = hs;
                if (write_lo) Clg[idx] = (_Float16)(v - (float)hs);
            }
        }
    }
}

// ---------------------------------------------------------------------------
// Layer 4 (P-layout hi only): one block per tile; t: row=t&127, half=t>>7
// ---------------------------------------------------------------------------
__global__ void layer4p(const _Float16* __restrict__ Ahg,
                        const float* __restrict__ w4,
                        const float* __restrict__ b4,
                        float* __restrict__ Amg, int row0) {
    __shared__ float ps[256];
    const int mt = blockIdx.x;
    const int t = threadIdx.x;
    const int row = t & 127, half = t >> 7;
    const int rowgrp = row >> 4, lidx = row & 15;
    const size_t base = ((size_t)(mt * 64) << 12) + rowgrp * 512 + lidx * 8;
    float s = 0.f;
    for (int kt = half * 32; kt < half * 32 + 32; ++kt) {
        const _Float16* ph = Ahg + base + ((size_t)kt << 12);
        const float* wv = w4 + kt * 32;
        #pragma unroll
        for (int quad = 0; quad < 4; ++quad) {
            f16x8 hv = *(const f16x8*)(ph + quad * 128);
            #pragma unroll
            for (int j = 0; j < 8; ++j)
                s += (float)hv[j] * wv[quad * 8 + j];
        }
    }
    ps[t] = s;
    __syncthreads();
    if (t < 128) {
        const int grow = row0 + mt * 128 + t;
        if (grow < MPTS) {
            float v = ps[t] + ps[t + 128] + b4[0];
            Amg[grow] = v > 0.f ? v : 0.f;
        }
    }
}

// ---------------------------------------------------------------------------
// Fallback fp32 path (ws too small for packed images)
// ---------------------------------------------------------------------------
__global__ void layer0f(const float* __restrict__ xs, const float* __restrict__ w0,
                        const float* __restrict__ b0, float* __restrict__ A, int row0) {
    const int r = blockIdx.x;
    const int j = threadIdx.x * 8;
    const float x = (row0 + r < MPTS) ? xs[row0 + r] : 0.f;
    float* out = A + (size_t)r * HID + j;
    #pragma unroll
    for (int q = 0; q < 8; ++q) {
        float v = x * w0[j + q] + b0[j + q];
        out[q] = v > 0.f ? v : 0.f;
    }
}

__launch_bounds__(256)
__global__ void gemm_valu(const float* __restrict__ A, const float* __restrict__ W,
                          const float* __restrict__ bias, float* __restrict__ C) {
    __shared__ float As[16][132];
    __shared__ float Ws[16][132];
    const int tid = threadIdx.x;
    const int tx = tid & 15, ty = tid >> 4;
    const int n0 = blockIdx.x * 128;
    const int m0 = blockIdx.y * 128;
    const int am = tid & 127, ak = (tid >> 7) * 8;
    const int wn = (tid & 15) * 8, wk = tid >> 4;
    const float* aptr = A + (size_t)(m0 + am) * HID + ak;
    const float* wptr = W + (size_t)wk * HID + n0 + wn;
    float acc[8][8];
    #pragma unroll
    for (int i = 0; i < 8; ++i)
        #pragma unroll
        for (int j = 0; j < 8; ++j) acc[i][j] = 0.f;
    for (int k0 = 0; k0 < HID; k0 += 16) {
        f32x4 a0 = *(const f32x4*)(aptr + k0);
        f32x4 a1 = *(const f32x4*)(aptr + k0 + 4);
        f32x4 w0v = *(const f32x4*)(wptr + (size_t)k0 * HID);
        f32x4 w1v = *(const f32x4*)(wptr + (size_t)k0 * HID + 4);
        __syncthreads();
        As[ak + 0][am] = a0[0]; As[ak + 1][am] = a0[1];
        As[ak + 2][am] = a0[2]; As[ak + 3][am] = a0[3];
        As[ak + 4][am] = a1[0]; As[ak + 5][am] = a1[1];
        As[ak + 6][am] = a1[2]; As[ak + 7][am] = a1[3];
        *(f32x4*)&Ws[wk][wn]     = w0v;
        *(f32x4*)&Ws[wk][wn + 4] = w1v;
        __syncthreads();
        #pragma unroll
        for (int kk = 0; kk < 16; ++kk) {
            f32x4 av0 = *(const f32x4*)&As[kk][ty * 8];
            f32x4 av1 = *(const f32x4*)&As[kk][ty * 8 + 4];
            f32x4 bv0 = *(const f32x4*)&Ws[kk][tx * 8];
            f32x4 bv1 = *(const f32x4*)&Ws[kk][tx * 8 + 4];
            float a[8] = {av0[0], av0[1], av0[2], av0[3], av1[0], av1[1], av1[2], av1[3]};
            float b[8] = {bv0[0], bv0[1], bv0[2], bv0[3], bv1[0], bv1[1], bv1[2], bv1[3]};
            #pragma unroll
            for (int i = 0; i < 8; ++i)
                #pragma unroll
                for (int j = 0; j < 8; ++j) acc[i][j] += a[i] * b[j];
        }
    }
    #pragma unroll
    for (int i = 0; i < 8; ++i) {
        const int m = m0 + ty * 8 + i;
        #pragma unroll
        for (int jc = 0; jc < 2; ++jc) {
            const int n = n0 + tx * 8 + jc * 4;
            f32x4 v4;
            #pragma unroll
            for (int q = 0; q < 4; ++q) {
                float v = acc[i][jc * 4 + q] + bias[n + q];
                v4[q] = v > 0.f ? v : 0.f;
            }
            *(f32x4*)(C + (size_t)m * HID + n) = v4;
        }
    }
}

__global__ void layer4f(const float* __restrict__ A, const float* __restrict__ w4,
                        const float* __restrict__ b4, float* __restrict__ Amg, int row0) {
    const int lane = threadIdx.x & 63;
    const int wave = threadIdx.x >> 6;
    const int r    = blockIdx.x * 4 + wave;
    if (row0 + r >= MPTS) return;
    const float* ap = A + (size_t)r * HID;
    float s = 0.f;
    #pragma unroll
    for (int c = 0; c < 8; ++c) {
        const int col = c * 256 + lane * 4;
        f32x4 av = *(const f32x4*)(ap + col);
        f32x4 wv = *(const f32x4*)(w4 + col);
        s += av[0] * wv[0] + av[1] * wv[1] + av[2] * wv[2] + av[3] * wv[3];
    }
    #pragma unroll
    for (int off = 32; off; off >>= 1) s += __shfl_down(s, off);
    if (lane == 0) {
        float v = s + b4[0];
        Amg[row0 + r] = v > 0.f ? v : 0.f;
    }
}

// ---------------------------------------------------------------------------
// Multigrid level: interp (2n-1) + band overwrite; all fp32 (d_out is fp32).
// ---------------------------------------------------------------------------
__global__ void mg_level(const float* __restrict__ in, float* __restrict__ outf,
                         const int* __restrict__ nbrs_base, int level,
                         const float* __restrict__ band, int n_out) {
    const int j = blockIdx.x * 256 + threadIdx.x;
    if (j >= n_out) return;
    float v;
    if (j & 1) v = 0.5f * (in[j >> 1] + in[(j >> 1) + 1]);
    else       v = in[j >> 1];
    const int stride =
        (nbrs_base[1] == 0 && nbrs_base[3] == 0 && nbrs_base[5] == 0) ? 2 : 1;
    #pragma unroll
    for (int t = 0; t < 8; ++t) {
        const int idx = nbrs_base[(level * 8 + t) * stride];
        if (j == idx) v = band[t];
    }
    outf[j] = v;
}

// ---------------------------------------------------------------------------
extern "C" void kernel_launch(void* const* d_in, const int* in_sizes, int n_in,
                              void* d_out, int out_size, void* d_ws, size_t ws_size,
                              hipStream_t stream) {
    // ---- input order detection: dict (documented) / signature / alphabetical
    int iXS=0, iNB=1, iW0=4, iB0=5, iW1=6, iB1=7, iW2=8, iB2=9,
        iW3=10, iB3=11, iW4=12, iB4=13;                       // dict default
    if (n_in >= 14) {
        if (in_sizes[0] == HID) {
            iB0=0; iB1=1; iB2=2; iB3=3; iB4=4; iNB=7;
            iW0=8; iW1=9; iW2=10; iW3=11; iW4=12; iXS=13;
        } else if (!(in_sizes[1] == 40 || in_sizes[1] == 80)) {
            iXS=0; iW0=1; iB0=2; iW1=3; iB1=4; iW2=5; iB2=6;
            iW3=7; iB3=8; iW4=9; iB4=10; iNB=11;
        }
    }
    const float* xs = (const float*)d_in[iXS];
    const int* nbrs = (const int*)d_in[iNB];
    const float* w0 = (const float*)d_in[iW0];
    const float* b0 = (const float*)d_in[iB0];
    const float* w1 = (const float*)d_in[iW1];
    const float* b1 = (const float*)d_in[iB1];
    const float* w2 = (const float*)d_in[iW2];
    const float* b2 = (const float*)d_in[iB2];
    const float* w3 = (const float*)d_in[iW3];
    const float* b3 = (const float*)d_in[iB3];
    const float* w4 = (const float*)d_in[iW4];
    const float* b4 = (const float*)d_in[iB4];

    // ---- workspace layout ----
    char* ws = (char*)d_ws;
    const size_t szAmg = 66048;
    const size_t szAh1 = 524544;
    const size_t szAh2 = 1048832;
    float* Amg = (float*)(ws);
    float* ahA = (float*)(ws + szAmg);
    float* ahB = (float*)(ws + szAmg + szAh1);
    const size_t casc_end = szAmg + szAh1 + szAh2;       // 1,639,424
    const size_t szW    = (size_t)3 * 1024 * BIMG * 2 + 4096; // fp16 images + ring-overrun pad
    const size_t per_tile = 2ull * 128 * HID * 4;        // 2 MB (4 fp16 act bufs)

    const int use_mfma = (ws_size >= casc_end + szW + per_tile) ? 1 : 0;

    _Float16* wp = (_Float16*)(ws + casc_end);
    const size_t buf_start = use_mfma ? (casc_end + szW) : casc_end;

    size_t avail = ws_size - buf_start;
    int CT = (int)(avail / per_tile);
    if (CT < 1) CT = 1;
    if (CT > 96) CT = 96;   // 96x16=1536 blocks: 2 exact rounds at 3 blk/CU

    if (use_mfma) {
        const size_t half = (size_t)CT * 128 * HID;       // f16 elems per buffer
        _Float16* bAh = (_Float16*)(ws + buf_start);
        _Float16* bAl = bAh + half;
        _Float16* bBh = bAh + 2 * half;
        _Float16* bBl = bAh + 3 * half;

        pack_w16<<<dim3(KTIL, NTIL, 3), 256, 0, stream>>>(w1, w2, w3, wp);

        for (int t0 = 0; t0 < MTILES; t0 += CT) {
            int tiles = (MTILES - t0 < CT) ? (MTILES - t0) : CT;
            int row0 = t0 * 128;
            layer0p<<<dim3(tiles * 128), 256, 0, stream>>>(xs, w0, b0, bAh, bAl, row0);
            dim3 ggrid(NTIL, tiles);
            gemm_hl<<<ggrid, 256, 0, stream>>>(bAh, bAl, wp, b1, bBh, bBl, 0, 1);
            gemm_hl<<<ggrid, 256, 0, stream>>>(bBh, bBl, wp, b2, bAh, bAl, 1, 1);
            gemm_hl<<<ggrid, 256, 0, stream>>>(bAh, bAl, wp, b3, bBh, bBl, 2, 0);
            layer4p<<<dim3(tiles), 256, 0, stream>>>(bBh, w4, b4, Amg, row0);
        }
    } else {
        float* bufA = (float*)(ws + buf_start);
        float* bufB = (float*)(ws + buf_start + (size_t)CT * 128 * HID * 4);
        for (int t0 = 0; t0 < MTILES; t0 += CT) {
            int tiles = (MTILES - t0 < CT) ? (MTILES - t0) : CT;
            int row0 = t0 * 128;
            layer0f<<<dim3(tiles * 128), 256, 0, stream>>>(xs, w0, b0, bufA, row0);
            dim3 ggrid(NTIL, tiles);
            gemm_valu<<<ggrid, 256, 0, stream>>>(bufA, w1, b1, bufB);
            gemm_valu<<<ggrid, 256, 0, stream>>>(bufB, w2, b2, bufA);
            gemm_valu<<<ggrid, 256, 0, stream>>>(bufA, w3, b3, bufB);
            layer4f<<<dim3(tiles * 32), 256, 0, stream>>>(bufB, w4, b4, Amg, row0);
        }
    }

    // multigrid cascade: 16385 -> ... -> 524289; level 4 writes d_out (fp32)
    const float* cur = Amg + 40;
    float* dsts[5] = {ahA, ahB, ahA, ahB, (float*)d_out};
    int n = 16385;
    for (int i = 0; i < 5; ++i) {
        int n_out = 2 * n - 1;
        mg_level<<<dim3((n_out + 255) / 256), 256, 0, stream>>>(
            cur, dsts[i], nbrs, i, Amg + 8 * (4 - i), n_out);
        cur = dsts[i];
        n = n_out;
    }
    (void)out_size;
}

// Round 7
// 1005.523 us; speedup vs baseline: 1.2933x; 1.2933x over previous
//
#include <hip/hip_runtime.h>
#include <stdint.h>

#define HID    2048
#define MPTS   16425
#define MTILES 129    // ceil(16425/128)
#define NTIL   16     // 2048/128
#define KTIL   64     // 2048/32
#define BIMG   5120   // f16 elems per packed padded B tile image (128 rows * 40)

typedef float    f32x4 __attribute__((ext_vector_type(4)));
typedef _Float16 f16x8 __attribute__((ext_vector_type(8)));

// P-layout (A-operand fragment order) for activations:
// elem(row, k) -> linear ((tile*64+kt)<<12) + rowgrp*512 + quad*128 + lidx*8 + j
//   tile=row>>7, rowgrp=(row>>4)&7, lidx=row&15, kt=k>>5, quad=(k>>3)&3, j=k&7
// Consumer wave A-frag load = base + lane*8 halves (1KB fully coalesced).

// ---------------------------------------------------------------------------
// Pack fp32 W (K x N row-major) into single-fp16 padded tile images:
// img(L,nt,kt)[n*40+k] = (f16)W[kt*32+k][nt*128+n]; pad k=32..39 zeros.
// ---------------------------------------------------------------------------
__global__ void pack_w16(const float* __restrict__ w1,
                         const float* __restrict__ w2,
                         const float* __restrict__ w3,
                         _Float16* __restrict__ wp) {
    const int kt = blockIdx.x, nt = blockIdx.y, L = blockIdx.z;
    const float* W = (L == 0) ? w1 : ((L == 1) ? w2 : w3);
    __shared__ float tl[128 * 33];   // [n][k] transposed, padded
    const int tid = threadIdx.x;
    const int k  = tid >> 3;          // 0..31
    const int nc = (tid & 7) * 16;    // 0..112
    const float* src = W + (size_t)(kt * 32 + k) * HID + nt * 128 + nc;
    #pragma unroll
    for (int j = 0; j < 16; ++j) tl[(nc + j) * 33 + k] = src[j];
    __syncthreads();
    const size_t base = (size_t)(L * 1024 + nt * 64 + kt) * BIMG;
    for (int e = tid; e < BIMG; e += 256) {
        int n = e / 40, kk = e - n * 40;
        wp[base + e] = (kk < 32) ? (_Float16)tl[n * 33 + kk] : (_Float16)0.f;
    }
}

// ---------------------------------------------------------------------------
// Layer 0: v=relu(xs*w0+b0); store fp16 hi/lo pair in P-layout
// ---------------------------------------------------------------------------
__global__ void layer0p(const float* __restrict__ xs,
                        const float* __restrict__ w0,
                        const float* __restrict__ b0,
                        _Float16* __restrict__ Ahg,
                        _Float16* __restrict__ Alg, int row0) {
    const int r = blockIdx.x;             // chunk-local row
    const int grow = row0 + r;
    const int j0 = threadIdx.x * 8;       // k
    const float x = (grow < MPTS) ? xs[grow] : 0.f;
    f16x8 h, l;
    #pragma unroll
    for (int q = 0; q < 8; ++q) {
        float v = x * w0[j0 + q] + b0[j0 + q];
        v = v > 0.f ? v : 0.f;
        _Float16 hs = (_Float16)v;
        h[q] = hs;
        l[q] = (_Float16)(v - (float)hs);
    }
    const int t = r >> 7, rowgrp = (r >> 4) & 7, lidx = r & 15;
    const int kt = j0 >> 5, quad = (j0 >> 3) & 3;
    const size_t dst = ((size_t)(t * 64 + kt) << 12) + rowgrp * 512 + quad * 128 + lidx * 8;
    *(f16x8*)(Ahg + dst) = h;
    *(f16x8*)(Alg + dst) = l;
}

// ---------------------------------------------------------------------------
// MFMA GEMM v12 (fp16): round-3 superstep-2 base (the traffic-safe profile:
// distance-1 prefetch, per-superstep drain -> blocks stay in kt-lockstep,
// preserving cross-block W-stream L2 sharing; r1/r6 proved counted deep
// pipelines break that sharing and inflate traffic 2-3x). Two changes:
//  (1) PARTIAL drain: A(2s+2) loads are issued AFTER the PFs, so
//      s_waitcnt vmcnt(8) + raw s_barrier drains exactly the PF chunks
//      (per-wave 2-3 ops, ~1200cyc old) while the 8 fresh A-loads stay in
//      flight across the barrier (consumed next superstep). Removes the
//      ~200-300cyc A round-trip that __syncthreads' vmcnt(0) ate per step.
//  (2) optional fused layer-4 epilogue (Amg4 != nullptr): dot fp32 acc rows
//      with w4, 16-lane shuffle reduce, one atomicAdd per row. relu(x+b4)
//      is applied later in mg_level. Removes gemm3's C write + layer4p.
// Accumulation order of the K-loop identical to v7-v10.
// ---------------------------------------------------------------------------
__launch_bounds__(256, 3)
__global__ void gemm_hl(const _Float16* __restrict__ Ahg,
                        const _Float16* __restrict__ Alg,
                        const _Float16* __restrict__ wp,
                        const float* __restrict__ bias,
                        _Float16* __restrict__ Chg,
                        _Float16* __restrict__ Clg,
                        int layer, int write_lo,
                        float* __restrict__ Amg4,
                        const float* __restrict__ w4g, int row0) {
    __shared__ _Float16 Bs[4][BIMG];   // 4 x 10240 B = 40 KB

    const int tid  = threadIdx.x;
    const int lane = tid & 63;
    const int wave = tid >> 6;
    const int quad = lane >> 4;
    const int lidx = lane & 15;

    // T1: bijective XCD-chunked swizzle (nwg = 16*tiles, always % 8 == 0).
    const int nwg = (int)(gridDim.x * gridDim.y);
    const int L   = (int)(blockIdx.y * gridDim.x + blockIdx.x);
    const int F   = (L & 7) * (nwg >> 3) + (L >> 3);
    const int nt  = F & 15;             // gridDim.x == NTIL == 16
    const int mt  = F >> 4;             // chunk-local tile

    const int mbase = (wave >> 1) * 64;
    const int nbase = (wave & 1) * 64;

    const char* gW = (const char*)(wp + (size_t)(layer * 1024 + nt * 64) * BIMG);

    const size_t abase = ((size_t)(mt * 64) << 12) + (size_t)(mbase >> 4) * 512 + (size_t)lane * 8;
    const _Float16* aH = Ahg + abase;
    const _Float16* aL = Alg + abase;

    f32x4 acc[4][4];
    #pragma unroll
    for (int i = 0; i < 4; ++i)
        #pragma unroll
        for (int j = 0; j < 4; ++j) acc[i][j] = (f32x4)0.f;

#define PF_B(KT, BUF) do {                                                            \
    const char* nW_ = gW + (size_t)(KT) * (BIMG * 2);                                 \
    char* dW_ = (char*)&Bs[BUF][0];                                                   \
    for (int t = wave; t < 10; t += 4) {                                              \
        __builtin_amdgcn_global_load_lds(                                             \
            (const __attribute__((address_space(1))) unsigned int*)(nW_ + t * 1024 + lane * 16), \
            (__attribute__((address_space(3))) unsigned int*)(dW_ + t * 1024), 16, 0, 0); \
    }                                                                                 \
} while (0)

#define LD_A(KT, H, Lo) do {                                                          \
    const size_t ak_ = (size_t)(KT) << 12;                                            \
    _Pragma("unroll")                                                                 \
    for (int mm = 0; mm < 4; ++mm) {                                                  \
        H[mm]  = *(const f16x8*)(aH + ak_ + mm * 512);                                \
        Lo[mm] = *(const f16x8*)(aL + ak_ + mm * 512);                                \
    }                                                                                 \
} while (0)

#define LD_B(BUF, BF) do {                                                            \
    _Pragma("unroll")                                                                 \
    for (int nn = 0; nn < 4; ++nn) {                                                  \
        int r_ = nbase + nn * 16 + lidx;                                              \
        BF[nn] = *(const f16x8*)(&Bs[BUF][r_ * 40 + quad * 8]);                       \
    }                                                                                 \
} while (0)

#define MFMA32(AH, AL, BF) do {                                                       \
    _Pragma("unroll")                                                                 \
    for (int mm = 0; mm < 4; ++mm)                                                    \
        _Pragma("unroll")                                                             \
        for (int nn = 0; nn < 4; ++nn) {                                              \
            acc[mm][nn] = __builtin_amdgcn_mfma_f32_16x16x32_f16(AH[mm], BF[nn], acc[mm][nn], 0, 0, 0); \
            acc[mm][nn] = __builtin_amdgcn_mfma_f32_16x16x32_f16(AL[mm], BF[nn], acc[mm][nn], 0, 0, 0); \
        }                                                                             \
} while (0)

// Partial-drain gate: PFs (issued before the A-loads, in-order retirement)
// are drained; the 8 youngest ops (A-loads for the next superstep) stay in
// flight across the barrier. LDS reads are already consumed by the MFMAs.
#define GATE8() do {                                                                  \
    asm volatile("s_waitcnt vmcnt(8)" ::: "memory");                                  \
    __builtin_amdgcn_sched_barrier(0);                                                \
    __builtin_amdgcn_s_barrier();                                                     \
    __builtin_amdgcn_sched_barrier(0);                                                \
} while (0)

// SUPER(s): kt = 2s, 2s+1 from buffer pair P; prefetch pair P^1; 1 barrier.
// Op order per wave: PF (2-3) -> A(2s+1) (8) -> A(2s+2) (8) -> gate.
#define SUPER(S, P, DO_PF, DO_A2) do {                                                \
    f16x8 bfr0_[4];                                                                   \
    LD_B(2 * (P), bfr0_);                                                             \
    if (DO_PF) { PF_B(2 * (S) + 2, 2 * ((P) ^ 1)); PF_B(2 * (S) + 3, 2 * ((P) ^ 1) + 1); } \
    LD_A(2 * (S) + 1, nah, nal);                                                      \
    MFMA32(cah, cal, bfr0_);                                                          \
    f16x8 bfr1_[4];                                                                   \
    LD_B(2 * (P) + 1, bfr1_);                                                         \
    if (DO_A2) LD_A(2 * (S) + 2, cah, cal);                                           \
    MFMA32(nah, nal, bfr1_);                                                          \
    GATE8();                                                                          \
} while (0)

    f16x8 cah[4], cal[4], nah[4], nal[4];

    // prologue: stage images 0,1 into bufs 0,1; preload A[0]; full drain once.
    PF_B(0, 0);
    PF_B(1, 1);
    LD_A(0, cah, cal);
    __syncthreads();

    // 32 supersteps = 64 kt; pair parity unrolled (LDS offsets static)
    for (int ss = 0; ss < 15; ++ss) {
        SUPER(2 * ss,     0, 1, 1);
        SUPER(2 * ss + 1, 1, 1, 1);
    }
    SUPER(30, 0, 1, 1);
    SUPER(31, 1, 0, 0);

#undef SUPER
#undef GATE8
#undef MFMA32
#undef LD_B
#undef LD_A
#undef PF_B

    if (Amg4) {
        // fused layer 4: h3 = relu(acc + b3); partial = h3 . w4 per row;
        // reduce over the 16 lidx lanes (cols) and atomically accumulate.
        // relu(x + b4) is applied when mg_level reads Amg.
        float w4v[4], bv[4];
        #pragma unroll
        for (int nn = 0; nn < 4; ++nn) {
            const int col = nt * 128 + nbase + nn * 16 + lidx;
            w4v[nn] = w4g[col];
            bv[nn]  = bias[col];
        }
        #pragma unroll
        for (int mm = 0; mm < 4; ++mm) {
            #pragma unroll
            for (int r = 0; r < 4; ++r) {
                float p = 0.f;
                #pragma unroll
                for (int nn = 0; nn < 4; ++nn) {
                    float v = acc[mm][nn][r] + bv[nn];
                    v = v > 0.f ? v : 0.f;
                    p += v * w4v[nn];
                }
                #pragma unroll
                for (int off = 1; off <= 8; off <<= 1)
                    p += __shfl_xor(p, off, 16);
                if (lidx == 0) {
                    const int grow = row0 + mt * 128 + mbase + mm * 16 + quad * 4 + r;
                    if (grow < MPTS) atomicAdd(Amg4 + grow, p);
                }
            }
        }
        return;
    }

    // epilogue: C/D layout col=lane&15, row=quad*4+reg; write P-layout pair
    #pragma unroll
    for (int nn = 0; nn < 4; ++nn) {
        const int col = nt * 128 + nbase + nn * 16 + lidx;   // k of next layer
        const float bv = bias[col];
        const int kt2 = col >> 5, quad2 = (col >> 3) & 3, j2 = col & 7;
        const size_t cb = ((size_t)(mt * 64 + kt2) << 12) + quad2 * 128 + j2;
        #pragma unroll
        for (int mm = 0; mm < 4; ++mm) {
            const int rowg = (mbase >> 4) + mm;             // rowgrp
            #pragma unroll
            for (int r = 0; r < 4; ++r) {
                const int lidx2 = quad * 4 + r;             // row & 15
                float v = acc[mm][nn][r] + bv;
                v = v > 0.f ? v : 0.f;
                _Float16 hs = (_Float16)v;
                const size_t idx = cb + rowg * 512 + lidx2 * 8;
                Chg[idx] = hs;
                if (write_lo) Clg[idx] = (_Float16)(v - (float)hs);
            }
        }
    }
}

// ---------------------------------------------------------------------------
// Fallback fp32 path (ws too small for packed images)
// ---------------------------------------------------------------------------
__global__ void layer0f(const float* __restrict__ xs, const float* __restrict__ w0,
                        const float* __restrict__ b0, float* __restrict__ A, int row0) {
    const int r = blockIdx.x;
    const int j = threadIdx.x * 8;
    const float x = (row0 + r < MPTS) ? xs[row0 + r] : 0.f;
    float* out = A + (size_t)r * HID + j;
    #pragma unroll
    for (int q = 0; q < 8; ++q) {
        float v = x * w0[j + q] + b0[j + q];
        out[q] = v > 0.f ? v : 0.f;
    }
}

__launch_bounds__(256)
__global__ void gemm_valu(const float* __restrict__ A, const float* __restrict__ W,
                          const float* __restrict__ bias, float* __restrict__ C) {
    __shared__ float As[16][132];
    __shared__ float Ws[16][132];
    const int tid = threadIdx.x;
    const int tx = tid & 15, ty = tid >> 4;
    const int n0 = blockIdx.x * 128;
    const int m0 = blockIdx.y * 128;
    const int am = tid & 127, ak = (tid >> 7) * 8;
    const int wn = (tid & 15) * 8, wk = tid >> 4;
    const float* aptr = A + (size_t)(m0 + am) * HID + ak;
    const float* wptr = W + (size_t)wk * HID + n0 + wn;
    float acc[8][8];
    #pragma unroll
    for (int i = 0; i < 8; ++i)
        #pragma unroll
        for (int j = 0; j < 8; ++j) acc[i][j] = 0.f;
    for (int k0 = 0; k0 < HID; k0 += 16) {
        f32x4 a0 = *(const f32x4*)(aptr + k0);
        f32x4 a1 = *(const f32x4*)(aptr + k0 + 4);
        f32x4 w0v = *(const f32x4*)(wptr + (size_t)k0 * HID);
        f32x4 w1v = *(const f32x4*)(wptr + (size_t)k0 * HID + 4);
        __syncthreads();
        As[ak + 0][am] = a0[0]; As[ak + 1][am] = a0[1];
        As[ak + 2][am] = a0[2]; As[ak + 3][am] = a0[3];
        As[ak + 4][am] = a1[0]; As[ak + 5][am] = a1[1];
        As[ak + 6][am] = a1[2]; As[ak + 7][am] = a1[3];
        *(f32x4*)&Ws[wk][wn]     = w0v;
        *(f32x4*)&Ws[wk][wn + 4] = w1v;
        __syncthreads();
        #pragma unroll
        for (int kk = 0; kk < 16; ++kk) {
            f32x4 av0 = *(const f32x4*)&As[kk][ty * 8];
            f32x4 av1 = *(const f32x4*)&As[kk][ty * 8 + 4];
            f32x4 bv0 = *(const f32x4*)&Ws[kk][tx * 8];
            f32x4 bv1 = *(const f32x4*)&Ws[kk][tx * 8 + 4];
            float a[8] = {av0[0], av0[1], av0[2], av0[3], av1[0], av1[1], av1[2], av1[3]};
            float b[8] = {bv0[0], bv0[1], bv0[2], bv0[3], bv1[0], bv1[1], bv1[2], bv1[3]};
            #pragma unroll
            for (int i = 0; i < 8; ++i)
                #pragma unroll
                for (int j = 0; j < 8; ++j) acc[i][j] += a[i] * b[j];
        }
    }
    #pragma unroll
    for (int i = 0; i < 8; ++i) {
        const int m = m0 + ty * 8 + i;
        #pragma unroll
        for (int jc = 0; jc < 2; ++jc) {
            const int n = n0 + tx * 8 + jc * 4;
            f32x4 v4;
            #pragma unroll
            for (int q = 0; q < 4; ++q) {
                float v = acc[i][jc * 4 + q] + bias[n + q];
                v4[q] = v > 0.f ? v : 0.f;
            }
            *(f32x4*)(C + (size_t)m * HID + n) = v4;
        }
    }
}

__global__ void layer4f(const float* __restrict__ A, const float* __restrict__ w4,
                        const float* __restrict__ b4, float* __restrict__ Amg, int row0) {
    const int lane = threadIdx.x & 63;
    const int wave = threadIdx.x >> 6;
    const int r    = blockIdx.x * 4 + wave;
    if (row0 + r >= MPTS) return;
    const float* ap = A + (size_t)r * HID;
    float s = 0.f;
    #pragma unroll
    for (int c = 0; c < 8; ++c) {
        const int col = c * 256 + lane * 4;
        f32x4 av = *(const f32x4*)(ap + col);
        f32x4 wv = *(const f32x4*)(w4 + col);
        s += av[0] * wv[0] + av[1] * wv[1] + av[2] * wv[2] + av[3] * wv[3];
    }
    #pragma unroll
    for (int off = 32; off; off >>= 1) s += __shfl_down(s, off);
    if (lane == 0) {
        float v = s + b4[0];
        Amg[row0 + r] = v > 0.f ? v : 0.f;
    }
}

// ---------------------------------------------------------------------------
// Multigrid level: interp (2n-1) + band overwrite; all fp32 (d_out is fp32).
// b4p non-null: apply f(x)=relu(x+b4) to band reads (Amg values are raw
// layer-4 sums from the fused gemm epilogue); xin: apply f to in[] too
// (level 0 only, where in[] comes straight from Amg).
// ---------------------------------------------------------------------------
__global__ void mg_level(const float* __restrict__ in, float* __restrict__ outf,
                         const int* __restrict__ nbrs_base, int level,
                         const float* __restrict__ band, int n_out,
                         const float* __restrict__ b4p, int xin) {
    const int j = blockIdx.x * 256 + threadIdx.x;
    if (j >= n_out) return;
    const float b4v = b4p ? b4p[0] : 0.f;
    float v;
    if (j & 1) {
        float a = in[j >> 1], b = in[(j >> 1) + 1];
        if (xin) { a = fmaxf(a + b4v, 0.f); b = fmaxf(b + b4v, 0.f); }
        v = 0.5f * (a + b);
    } else {
        float a = in[j >> 1];
        if (xin) a = fmaxf(a + b4v, 0.f);
        v = a;
    }
    const int stride =
        (nbrs_base[1] == 0 && nbrs_base[3] == 0 && nbrs_base[5] == 0) ? 2 : 1;
    #pragma unroll
    for (int t = 0; t < 8; ++t) {
        const int idx = nbrs_base[(level * 8 + t) * stride];
        if (j == idx) {
            float bb = band[t];
            if (b4p) bb = fmaxf(bb + b4v, 0.f);
            v = bb;
        }
    }
    outf[j] = v;
}

// ---------------------------------------------------------------------------
extern "C" void kernel_launch(void* const* d_in, const int* in_sizes, int n_in,
                              void* d_out, int out_size, void* d_ws, size_t ws_size,
                              hipStream_t stream) {
    // ---- input order detection: dict (documented) / signature / alphabetical
    int iXS=0, iNB=1, iW0=4, iB0=5, iW1=6, iB1=7, iW2=8, iB2=9,
        iW3=10, iB3=11, iW4=12, iB4=13;                       // dict default
    if (n_in >= 14) {
        if (in_sizes[0] == HID) {
            iB0=0; iB1=1; iB2=2; iB3=3; iB4=4; iNB=7;
            iW0=8; iW1=9; iW2=10; iW3=11; iW4=12; iXS=13;
        } else if (!(in_sizes[1] == 40 || in_sizes[1] == 80)) {
            iXS=0; iW0=1; iB0=2; iW1=3; iB1=4; iW2=5; iB2=6;
            iW3=7; iB3=8; iW4=9; iB4=10; iNB=11;
        }
    }
    const float* xs = (const float*)d_in[iXS];
    const int* nbrs = (const int*)d_in[iNB];
    const float* w0 = (const float*)d_in[iW0];
    const float* b0 = (const float*)d_in[iB0];
    const float* w1 = (const float*)d_in[iW1];
    const float* b1 = (const float*)d_in[iB1];
    const float* w2 = (const float*)d_in[iW2];
    const float* b2 = (const float*)d_in[iB2];
    const float* w3 = (const float*)d_in[iW3];
    const float* b3 = (const float*)d_in[iB3];
    const float* w4 = (const float*)d_in[iW4];
    const float* b4 = (const float*)d_in[iB4];

    // ---- workspace layout ----
    char* ws = (char*)d_ws;
    const size_t szAmg = 66048;
    const size_t szAh1 = 524544;
    const size_t szAh2 = 1048832;
    float* Amg = (float*)(ws);
    float* ahA = (float*)(ws + szAmg);
    float* ahB = (float*)(ws + szAmg + szAh1);
    const size_t casc_end = szAmg + szAh1 + szAh2;       // 1,639,424
    const size_t szW    = (size_t)3 * 1024 * BIMG * 2;   // 31,457,280 (fp16)
    const size_t per_tile = 2ull * 128 * HID * 4;        // 2 MB (4 fp16 act bufs)

    const int use_mfma = (ws_size >= casc_end + szW + per_tile) ? 1 : 0;

    _Float16* wp = (_Float16*)(ws + casc_end);
    const size_t buf_start = use_mfma ? (casc_end + szW) : casc_end;

    size_t avail = ws_size - buf_start;
    int CT = (int)(avail / per_tile);
    if (CT < 1) CT = 1;
    if (CT > 96) CT = 96;   // 96x16=1536 blocks: 2 exact rounds at 3 blk/CU

    if (use_mfma) {
        const size_t half = (size_t)CT * 128 * HID;       // f16 elems per buffer
        _Float16* bAh = (_Float16*)(ws + buf_start);
        _Float16* bAl = bAh + half;
        _Float16* bBh = bAh + 2 * half;
        _Float16* bBl = bAh + 3 * half;

        // fused layer-4 accumulates into Amg -> zero it (stream-ordered).
        hipMemsetAsync(Amg, 0, (size_t)MPTS * sizeof(float), stream);

        pack_w16<<<dim3(KTIL, NTIL, 3), 256, 0, stream>>>(w1, w2, w3, wp);

        for (int t0 = 0; t0 < MTILES; t0 += CT) {
            int tiles = (MTILES - t0 < CT) ? (MTILES - t0) : CT;
            int row0 = t0 * 128;
            layer0p<<<dim3(tiles * 128), 256, 0, stream>>>(xs, w0, b0, bAh, bAl, row0);
            dim3 ggrid(NTIL, tiles);
            gemm_hl<<<ggrid, 256, 0, stream>>>(bAh, bAl, wp, b1, bBh, bBl, 0, 1,
                                               nullptr, nullptr, 0);
            gemm_hl<<<ggrid, 256, 0, stream>>>(bBh, bBl, wp, b2, bAh, bAl, 1, 1,
                                               nullptr, nullptr, 0);
            // layer 2->3 gemm with fused layer-4 dot (no C write, no layer4p)
            gemm_hl<<<ggrid, 256, 0, stream>>>(bAh, bAl, wp, b3, bBh, bBl, 2, 0,
                                               Amg, w4, row0);
        }
    } else {
        float* bufA = (float*)(ws + buf_start);
        float* bufB = (float*)(ws + buf_start + (size_t)CT * 128 * HID * 4);
        for (int t0 = 0; t0 < MTILES; t0 += CT) {
            int tiles = (MTILES - t0 < CT) ? (MTILES - t0) : CT;
            int row0 = t0 * 128;
            layer0f<<<dim3(tiles * 128), 256, 0, stream>>>(xs, w0, b0, bufA, row0);
            dim3 ggrid(NTIL, tiles);
            gemm_valu<<<ggrid, 256, 0, stream>>>(bufA, w1, b1, bufB);
            gemm_valu<<<ggrid, 256, 0, stream>>>(bufB, w2, b2, bufA);
            gemm_valu<<<ggrid, 256, 0, stream>>>(bufA, w3, b3, bufB);
            layer4f<<<dim3(tiles * 32), 256, 0, stream>>>(bufB, w4, b4, Amg, row0);
        }
    }

    // multigrid cascade: 16385 -> ... -> 524289; level 4 writes d_out (fp32).
    // mfma path: Amg holds raw layer-4 sums; relu(x+b4) applied at read.
    const float* b4p = use_mfma ? b4 : nullptr;
    const float* cur = Amg + 40;
    float* dsts[5] = {ahA, ahB, ahA, ahB, (float*)d_out};
    int n = 16385;
    for (int i = 0; i < 5; ++i) {
        int n_out = 2 * n - 1;
        mg_level<<<dim3((n_out + 255) / 256), 256, 0, stream>>>(
            cur, dsts[i], nbrs, i, Amg + 8 * (4 - i), n_out,
            b4p, (i == 0 && use_mfma) ? 1 : 0);
        cur = dsts[i];
        n = n_out;
    }
    (void)out_size;
}

// Round 8
// 914.602 us; speedup vs baseline: 1.4219x; 1.0994x over previous
//
#include <hip/hip_runtime.h>
#include <stdint.h>

#define HID    2048
#define MPTS   16425
#define MTILES 129    // ceil(16425/128)
#define NTIL   16     // 2048/128
#define KTIL   64     // 2048/32
#define BIMG   5120   // f16 elems per packed padded B tile image (128 rows * 40)

typedef float    f32x4 __attribute__((ext_vector_type(4)));
typedef _Float16 f16x8 __attribute__((ext_vector_type(8)));

// P-layout (A-operand fragment order) for activations:
// elem(row, k) -> linear ((tile*64+kt)<<12) + rowgrp*512 + quad*128 + lidx*8 + j
//   tile=row>>7, rowgrp=(row>>4)&7, lidx=row&15, kt=k>>5, quad=(k>>3)&3, j=k&7
// Consumer wave A-frag load = base + lane*8 halves (1KB fully coalesced).

// ---------------------------------------------------------------------------
// Pack fp32 W (K x N row-major) into single-fp16 padded tile images:
// img(L,nt,kt)[n*40+k] = (f16)W[kt*32+k][nt*128+n]; pad k=32..39 zeros.
// ---------------------------------------------------------------------------
__global__ void pack_w16(const float* __restrict__ w1,
                         const float* __restrict__ w2,
                         const float* __restrict__ w3,
                         _Float16* __restrict__ wp) {
    const int kt = blockIdx.x, nt = blockIdx.y, L = blockIdx.z;
    const float* W = (L == 0) ? w1 : ((L == 1) ? w2 : w3);
    __shared__ float tl[128 * 33];   // [n][k] transposed, padded
    const int tid = threadIdx.x;
    const int k  = tid >> 3;          // 0..31
    const int nc = (tid & 7) * 16;    // 0..112
    const float* src = W + (size_t)(kt * 32 + k) * HID + nt * 128 + nc;
    #pragma unroll
    for (int j = 0; j < 16; ++j) tl[(nc + j) * 33 + k] = src[j];
    __syncthreads();
    const size_t base = (size_t)(L * 1024 + nt * 64 + kt) * BIMG;
    for (int e = tid; e < BIMG; e += 256) {
        int n = e / 40, kk = e - n * 40;
        wp[base + e] = (kk < 32) ? (_Float16)tl[n * 33 + kk] : (_Float16)0.f;
    }
}

// ---------------------------------------------------------------------------
// Layer 0: v=relu(xs*w0+b0); store fp16 hi/lo pair in P-layout
// ---------------------------------------------------------------------------
__global__ void layer0p(const float* __restrict__ xs,
                        const float* __restrict__ w0,
                        const float* __restrict__ b0,
                        _Float16* __restrict__ Ahg,
                        _Float16* __restrict__ Alg, int row0) {
    const int r = blockIdx.x;             // chunk-local row
    const int grow = row0 + r;
    const int j0 = threadIdx.x * 8;       // k
    const float x = (grow < MPTS) ? xs[grow] : 0.f;
    f16x8 h, l;
    #pragma unroll
    for (int q = 0; q < 8; ++q) {
        float v = x * w0[j0 + q] + b0[j0 + q];
        v = v > 0.f ? v : 0.f;
        _Float16 hs = (_Float16)v;
        h[q] = hs;
        l[q] = (_Float16)(v - (float)hs);
    }
    const int t = r >> 7, rowgrp = (r >> 4) & 7, lidx = r & 15;
    const int kt = j0 >> 5, quad = (j0 >> 3) & 3;
    const size_t dst = ((size_t)(t * 64 + kt) << 12) + rowgrp * 512 + quad * 128 + lidx * 8;
    *(f16x8*)(Ahg + dst) = h;
    *(f16x8*)(Alg + dst) = l;
}

// ---------------------------------------------------------------------------
// MFMA GEMM v13 (fp16): wave retile 64x64 -> 32x128 to halve A L2-traffic.
// r7 arithmetic: pure-MFMA floor 142us, measured 198.7; co-limiter is L2
// read BW -- the old 2x4-wave grid made each A fragment load twice from
// global (4.1 GB L2/dispatch). New tiling: each of 4 waves owns 32 rows x
// all 128 cols -> A slice unique per wave (2.05 GB), B still shared via LDS.
//   per-wave: acc[2][8]=64 (AGPR) + A dbuf 2x(2x2 f16x8)=32 + B 8x f16x8
//   transient = same ~80 arch VGPR as r7 (no spill; (256,3) proven).
// MFMA count/order per output element unchanged (kt asc, hi then lo) ->
// bit-identical accumulation. Schedule = r7's: distance-1 PF, per-superstep
// partial-drain gate (now vmcnt(4): 4 A-loads/kt), XCD swizzle, fused L4.
// ---------------------------------------------------------------------------
__launch_bounds__(256, 3)
__global__ void gemm_hl(const _Float16* __restrict__ Ahg,
                        const _Float16* __restrict__ Alg,
                        const _Float16* __restrict__ wp,
                        const float* __restrict__ bias,
                        _Float16* __restrict__ Chg,
                        _Float16* __restrict__ Clg,
                        int layer, int write_lo,
                        float* __restrict__ Amg4,
                        const float* __restrict__ w4g, int row0) {
    __shared__ _Float16 Bs[4][BIMG];   // 4 x 10240 B = 40 KB

    const int tid  = threadIdx.x;
    const int lane = tid & 63;
    const int wave = tid >> 6;
    const int quad = lane >> 4;
    const int lidx = lane & 15;

    // T1: bijective XCD-chunked swizzle (nwg = 16*tiles, always % 8 == 0).
    const int nwg = (int)(gridDim.x * gridDim.y);
    const int L   = (int)(blockIdx.y * gridDim.x + blockIdx.x);
    const int F   = (L & 7) * (nwg >> 3) + (L >> 3);
    const int nt  = F & 15;             // gridDim.x == NTIL == 16
    const int mt  = F >> 4;             // chunk-local tile

    const int mbase = wave * 32;        // each wave: 32 rows x 128 cols

    const char* gW = (const char*)(wp + (size_t)(layer * 1024 + nt * 64) * BIMG);

    const size_t abase = ((size_t)(mt * 64) << 12) + (size_t)(mbase >> 4) * 512 + (size_t)lane * 8;
    const _Float16* aH = Ahg + abase;
    const _Float16* aL = Alg + abase;

    f32x4 acc[2][8];
    #pragma unroll
    for (int i = 0; i < 2; ++i)
        #pragma unroll
        for (int j = 0; j < 8; ++j) acc[i][j] = (f32x4)0.f;

#define PF_B(KT, BUF) do {                                                            \
    const char* nW_ = gW + (size_t)(KT) * (BIMG * 2);                                 \
    char* dW_ = (char*)&Bs[BUF][0];                                                   \
    for (int t = wave; t < 10; t += 4) {                                              \
        __builtin_amdgcn_global_load_lds(                                             \
            (const __attribute__((address_space(1))) unsigned int*)(nW_ + t * 1024 + lane * 16), \
            (__attribute__((address_space(3))) unsigned int*)(dW_ + t * 1024), 16, 0, 0); \
    }                                                                                 \
} while (0)

#define LD_A(KT, H, Lo) do {                                                          \
    const size_t ak_ = (size_t)(KT) << 12;                                            \
    _Pragma("unroll")                                                                 \
    for (int mm = 0; mm < 2; ++mm) {                                                  \
        H[mm]  = *(const f16x8*)(aH + ak_ + mm * 512);                                \
        Lo[mm] = *(const f16x8*)(aL + ak_ + mm * 512);                                \
    }                                                                                 \
} while (0)

#define LD_B(BUF, BF) do {                                                            \
    _Pragma("unroll")                                                                 \
    for (int nn = 0; nn < 8; ++nn) {                                                  \
        int r_ = nn * 16 + lidx;                                                      \
        BF[nn] = *(const f16x8*)(&Bs[BUF][r_ * 40 + quad * 8]);                       \
    }                                                                                 \
} while (0)

#define MFMA32(AH, AL, BF) do {                                                       \
    _Pragma("unroll")                                                                 \
    for (int mm = 0; mm < 2; ++mm)                                                    \
        _Pragma("unroll")                                                             \
        for (int nn = 0; nn < 8; ++nn) {                                              \
            acc[mm][nn] = __builtin_amdgcn_mfma_f32_16x16x32_f16(AH[mm], BF[nn], acc[mm][nn], 0, 0, 0); \
            acc[mm][nn] = __builtin_amdgcn_mfma_f32_16x16x32_f16(AL[mm], BF[nn], acc[mm][nn], 0, 0, 0); \
        }                                                                             \
} while (0)

// Partial-drain gate: drains PFs (issued first); the 4 youngest ops
// (A-loads for the next superstep) stay in flight across the barrier.
#define GATE4() do {                                                                  \
    asm volatile("s_waitcnt vmcnt(4)" ::: "memory");                                  \
    __builtin_amdgcn_sched_barrier(0);                                                \
    __builtin_amdgcn_s_barrier();                                                     \
    __builtin_amdgcn_sched_barrier(0);                                                \
} while (0)

// SUPER(s): kt = 2s, 2s+1 from buffer pair P; prefetch pair P^1; 1 barrier.
// Per-wave op order: PF (2-3) -> A(2s+1) (4) -> A(2s+2) (4) -> gate.
#define SUPER(S, P, DO_PF, DO_A2) do {                                                \
    f16x8 bfr0_[8];                                                                   \
    LD_B(2 * (P), bfr0_);                                                             \
    if (DO_PF) { PF_B(2 * (S) + 2, 2 * ((P) ^ 1)); PF_B(2 * (S) + 3, 2 * ((P) ^ 1) + 1); } \
    LD_A(2 * (S) + 1, nah, nal);                                                      \
    MFMA32(cah, cal, bfr0_);                                                          \
    f16x8 bfr1_[8];                                                                   \
    LD_B(2 * (P) + 1, bfr1_);                                                         \
    if (DO_A2) LD_A(2 * (S) + 2, cah, cal);                                           \
    MFMA32(nah, nal, bfr1_);                                                          \
    GATE4();                                                                          \
} while (0)

    f16x8 cah[2], cal[2], nah[2], nal[2];

    // prologue: stage images 0,1 into bufs 0,1; preload A[0]; full drain once.
    PF_B(0, 0);
    PF_B(1, 1);
    LD_A(0, cah, cal);
    __syncthreads();

    // 32 supersteps = 64 kt; pair parity unrolled (LDS offsets static)
    for (int ss = 0; ss < 15; ++ss) {
        SUPER(2 * ss,     0, 1, 1);
        SUPER(2 * ss + 1, 1, 1, 1);
    }
    SUPER(30, 0, 1, 1);
    SUPER(31, 1, 0, 0);

#undef SUPER
#undef GATE4
#undef MFMA32
#undef LD_B
#undef LD_A
#undef PF_B

    if (Amg4) {
        // fused layer 4: h3 = relu(acc + b3); partial = h3 . w4 per row;
        // reduce over the 16 lidx lanes (full 128 cols of this nt) and
        // atomically accumulate. relu(x + b4) applied in mg_level.
        float w4v[8], bv[8];
        #pragma unroll
        for (int nn = 0; nn < 8; ++nn) {
            const int col = nt * 128 + nn * 16 + lidx;
            w4v[nn] = w4g[col];
            bv[nn]  = bias[col];
        }
        #pragma unroll
        for (int mm = 0; mm < 2; ++mm) {
            #pragma unroll
            for (int r = 0; r < 4; ++r) {
                float p = 0.f;
                #pragma unroll
                for (int nn = 0; nn < 8; ++nn) {
                    float v = acc[mm][nn][r] + bv[nn];
                    v = v > 0.f ? v : 0.f;
                    p += v * w4v[nn];
                }
                #pragma unroll
                for (int off = 1; off <= 8; off <<= 1)
                    p += __shfl_xor(p, off, 16);
                if (lidx == 0) {
                    const int grow = row0 + mt * 128 + mbase + mm * 16 + quad * 4 + r;
                    if (grow < MPTS) atomicAdd(Amg4 + grow, p);
                }
            }
        }
        return;
    }

    // epilogue: C/D layout col=lane&15, row=quad*4+reg; write P-layout pair
    #pragma unroll
    for (int nn = 0; nn < 8; ++nn) {
        const int col = nt * 128 + nn * 16 + lidx;           // k of next layer
        const float bv = bias[col];
        const int kt2 = col >> 5, quad2 = (col >> 3) & 3, j2 = col & 7;
        const size_t cb = ((size_t)(mt * 64 + kt2) << 12) + quad2 * 128 + j2;
        #pragma unroll
        for (int mm = 0; mm < 2; ++mm) {
            const int rowg = (mbase >> 4) + mm;             // rowgrp
            #pragma unroll
            for (int r = 0; r < 4; ++r) {
                const int lidx2 = quad * 4 + r;             // row & 15
                float v = acc[mm][nn][r] + bv;
                v = v > 0.f ? v : 0.f;
                _Float16 hs = (_Float16)v;
                const size_t idx = cb + rowg * 512 + lidx2 * 8;
                Chg[idx] = hs;
                if (write_lo) Clg[idx] = (_Float16)(v - (float)hs);
            }
        }
    }
}

// ---------------------------------------------------------------------------
// Fallback fp32 path (ws too small for packed images)
// ---------------------------------------------------------------------------
__global__ void layer0f(const float* __restrict__ xs, const float* __restrict__ w0,
                        const float* __restrict__ b0, float* __restrict__ A, int row0) {
    const int r = blockIdx.x;
    const int j = threadIdx.x * 8;
    const float x = (row0 + r < MPTS) ? xs[row0 + r] : 0.f;
    float* out = A + (size_t)r * HID + j;
    #pragma unroll
    for (int q = 0; q < 8; ++q) {
        float v = x * w0[j + q] + b0[j + q];
        out[q] = v > 0.f ? v : 0.f;
    }
}

__launch_bounds__(256)
__global__ void gemm_valu(const float* __restrict__ A, const float* __restrict__ W,
                          const float* __restrict__ bias, float* __restrict__ C) {
    __shared__ float As[16][132];
    __shared__ float Ws[16][132];
    const int tid = threadIdx.x;
    const int tx = tid & 15, ty = tid >> 4;
    const int n0 = blockIdx.x * 128;
    const int m0 = blockIdx.y * 128;
    const int am = tid & 127, ak = (tid >> 7) * 8;
    const int wn = (tid & 15) * 8, wk = tid >> 4;
    const float* aptr = A + (size_t)(m0 + am) * HID + ak;
    const float* wptr = W + (size_t)wk * HID + n0 + wn;
    float acc[8][8];
    #pragma unroll
    for (int i = 0; i < 8; ++i)
        #pragma unroll
        for (int j = 0; j < 8; ++j) acc[i][j] = 0.f;
    for (int k0 = 0; k0 < HID; k0 += 16) {
        f32x4 a0 = *(const f32x4*)(aptr + k0);
        f32x4 a1 = *(const f32x4*)(aptr + k0 + 4);
        f32x4 w0v = *(const f32x4*)(wptr + (size_t)k0 * HID);
        f32x4 w1v = *(const f32x4*)(wptr + (size_t)k0 * HID + 4);
        __syncthreads();
        As[ak + 0][am] = a0[0]; As[ak + 1][am] = a0[1];
        As[ak + 2][am] = a0[2]; As[ak + 3][am] = a0[3];
        As[ak + 4][am] = a1[0]; As[ak + 5][am] = a1[1];
        As[ak + 6][am] = a1[2]; As[ak + 7][am] = a1[3];
        *(f32x4*)&Ws[wk][wn]     = w0v;
        *(f32x4*)&Ws[wk][wn + 4] = w1v;
        __syncthreads();
        #pragma unroll
        for (int kk = 0; kk < 16; ++kk) {
            f32x4 av0 = *(const f32x4*)&As[kk][ty * 8];
            f32x4 av1 = *(const f32x4*)&As[kk][ty * 8 + 4];
            f32x4 bv0 = *(const f32x4*)&Ws[kk][tx * 8];
            f32x4 bv1 = *(const f32x4*)&Ws[kk][tx * 8 + 4];
            float a[8] = {av0[0], av0[1], av0[2], av0[3], av1[0], av1[1], av1[2], av1[3]};
            float b[8] = {bv0[0], bv0[1], bv0[2], bv0[3], bv1[0], bv1[1], bv1[2], bv1[3]};
            #pragma unroll
            for (int i = 0; i < 8; ++i)
                #pragma unroll
                for (int j = 0; j < 8; ++j) acc[i][j] += a[i] * b[j];
        }
    }
    #pragma unroll
    for (int i = 0; i < 8; ++i) {
        const int m = m0 + ty * 8 + i;
        #pragma unroll
        for (int jc = 0; jc < 2; ++jc) {
            const int n = n0 + tx * 8 + jc * 4;
            f32x4 v4;
            #pragma unroll
            for (int q = 0; q < 4; ++q) {
                float v = acc[i][jc * 4 + q] + bias[n + q];
                v4[q] = v > 0.f ? v : 0.f;
            }
            *(f32x4*)(C + (size_t)m * HID + n) = v4;
        }
    }
}

__global__ void layer4f(const float* __restrict__ A, const float* __restrict__ w4,
                        const float* __restrict__ b4, float* __restrict__ Amg, int row0) {
    const int lane = threadIdx.x & 63;
    const int wave = threadIdx.x >> 6;
    const int r    = blockIdx.x * 4 + wave;
    if (row0 + r >= MPTS) return;
    const float* ap = A + (size_t)r * HID;
    float s = 0.f;
    #pragma unroll
    for (int c = 0; c < 8; ++c) {
        const int col = c * 256 + lane * 4;
        f32x4 av = *(const f32x4*)(ap + col);
        f32x4 wv = *(const f32x4*)(w4 + col);
        s += av[0] * wv[0] + av[1] * wv[1] + av[2] * wv[2] + av[3] * wv[3];
    }
    #pragma unroll
    for (int off = 32; off; off >>= 1) s += __shfl_down(s, off);
    if (lane == 0) {
        float v = s + b4[0];
        Amg[row0 + r] = v > 0.f ? v : 0.f;
    }
}

// ---------------------------------------------------------------------------
// Multigrid level: interp (2n-1) + band overwrite; all fp32 (d_out is fp32).
// b4p non-null: apply f(x)=relu(x+b4) to band reads (Amg values are raw
// layer-4 sums from the fused gemm epilogue); xin: apply f to in[] too
// (level 0 only, where in[] comes straight from Amg).
// ---------------------------------------------------------------------------
__global__ void mg_level(const float* __restrict__ in, float* __restrict__ outf,
                         const int* __restrict__ nbrs_base, int level,
                         const float* __restrict__ band, int n_out,
                         const float* __restrict__ b4p, int xin) {
    const int j = blockIdx.x * 256 + threadIdx.x;
    if (j >= n_out) return;
    const float b4v = b4p ? b4p[0] : 0.f;
    float v;
    if (j & 1) {
        float a = in[j >> 1], b = in[(j >> 1) + 1];
        if (xin) { a = fmaxf(a + b4v, 0.f); b = fmaxf(b + b4v, 0.f); }
        v = 0.5f * (a + b);
    } else {
        float a = in[j >> 1];
        if (xin) a = fmaxf(a + b4v, 0.f);
        v = a;
    }
    const int stride =
        (nbrs_base[1] == 0 && nbrs_base[3] == 0 && nbrs_base[5] == 0) ? 2 : 1;
    #pragma unroll
    for (int t = 0; t < 8; ++t) {
        const int idx = nbrs_base[(level * 8 + t) * stride];
        if (j == idx) {
            float bb = band[t];
            if (b4p) bb = fmaxf(bb + b4v, 0.f);
            v = bb;
        }
    }
    outf[j] = v;
}

// ---------------------------------------------------------------------------
extern "C" void kernel_launch(void* const* d_in, const int* in_sizes, int n_in,
                              void* d_out, int out_size, void* d_ws, size_t ws_size,
                              hipStream_t stream) {
    // ---- input order detection: dict (documented) / signature / alphabetical
    int iXS=0, iNB=1, iW0=4, iB0=5, iW1=6, iB1=7, iW2=8, iB2=9,
        iW3=10, iB3=11, iW4=12, iB4=13;                       // dict default
    if (n_in >= 14) {
        if (in_sizes[0] == HID) {
            iB0=0; iB1=1; iB2=2; iB3=3; iB4=4; iNB=7;
            iW0=8; iW1=9; iW2=10; iW3=11; iW4=12; iXS=13;
        } else if (!(in_sizes[1] == 40 || in_sizes[1] == 80)) {
            iXS=0; iW0=1; iB0=2; iW1=3; iB1=4; iW2=5; iB2=6;
            iW3=7; iB3=8; iW4=9; iB4=10; iNB=11;
        }
    }
    const float* xs = (const float*)d_in[iXS];
    const int* nbrs = (const int*)d_in[iNB];
    const float* w0 = (const float*)d_in[iW0];
    const float* b0 = (const float*)d_in[iB0];
    const float* w1 = (const float*)d_in[iW1];
    const float* b1 = (const float*)d_in[iB1];
    const float* w2 = (const float*)d_in[iW2];
    const float* b2 = (const float*)d_in[iB2];
    const float* w3 = (const float*)d_in[iW3];
    const float* b3 = (const float*)d_in[iB3];
    const float* w4 = (const float*)d_in[iW4];
    const float* b4 = (const float*)d_in[iB4];

    // ---- workspace layout ----
    char* ws = (char*)d_ws;
    const size_t szAmg = 66048;
    const size_t szAh1 = 524544;
    const size_t szAh2 = 1048832;
    float* Amg = (float*)(ws);
    float* ahA = (float*)(ws + szAmg);
    float* ahB = (float*)(ws + szAmg + szAh1);
    const size_t casc_end = szAmg + szAh1 + szAh2;       // 1,639,424
    const size_t szW    = (size_t)3 * 1024 * BIMG * 2;   // 31,457,280 (fp16)
    const size_t per_tile = 2ull * 128 * HID * 4;        // 2 MB (4 fp16 act bufs)

    const int use_mfma = (ws_size >= casc_end + szW + per_tile) ? 1 : 0;

    _Float16* wp = (_Float16*)(ws + casc_end);
    const size_t buf_start = use_mfma ? (casc_end + szW) : casc_end;

    size_t avail = ws_size - buf_start;
    int CT = (int)(avail / per_tile);
    if (CT < 1) CT = 1;
    if (CT > 96) CT = 96;   // 96x16=1536 blocks: 2 exact rounds at 3 blk/CU

    if (use_mfma) {
        const size_t half = (size_t)CT * 128 * HID;       // f16 elems per buffer
        _Float16* bAh = (_Float16*)(ws + buf_start);
        _Float16* bAl = bAh + half;
        _Float16* bBh = bAh + 2 * half;
        _Float16* bBl = bAh + 3 * half;

        // fused layer-4 accumulates into Amg -> zero it (stream-ordered).
        hipMemsetAsync(Amg, 0, (size_t)MPTS * sizeof(float), stream);

        pack_w16<<<dim3(KTIL, NTIL, 3), 256, 0, stream>>>(w1, w2, w3, wp);

        for (int t0 = 0; t0 < MTILES; t0 += CT) {
            int tiles = (MTILES - t0 < CT) ? (MTILES - t0) : CT;
            int row0 = t0 * 128;
            layer0p<<<dim3(tiles * 128), 256, 0, stream>>>(xs, w0, b0, bAh, bAl, row0);
            dim3 ggrid(NTIL, tiles);
            gemm_hl<<<ggrid, 256, 0, stream>>>(bAh, bAl, wp, b1, bBh, bBl, 0, 1,
                                               nullptr, nullptr, 0);
            gemm_hl<<<ggrid, 256, 0, stream>>>(bBh, bBl, wp, b2, bAh, bAl, 1, 1,
                                               nullptr, nullptr, 0);
            // layer 2->3 gemm with fused layer-4 dot (no C write, no layer4p)
            gemm_hl<<<ggrid, 256, 0, stream>>>(bAh, bAl, wp, b3, bBh, bBl, 2, 0,
                                               Amg, w4, row0);
        }
    } else {
        float* bufA = (float*)(ws + buf_start);
        float* bufB = (float*)(ws + buf_start + (size_t)CT * 128 * HID * 4);
        for (int t0 = 0; t0 < MTILES; t0 += CT) {
            int tiles = (MTILES - t0 < CT) ? (MTILES - t0) : CT;
            int row0 = t0 * 128;
            layer0f<<<dim3(tiles * 128), 256, 0, stream>>>(xs, w0, b0, bufA, row0);
            dim3 ggrid(NTIL, tiles);
            gemm_valu<<<ggrid, 256, 0, stream>>>(bufA, w1, b1, bufB);
            gemm_valu<<<ggrid, 256, 0, stream>>>(bufB, w2, b2, bufA);
            gemm_valu<<<ggrid, 256, 0, stream>>>(bufA, w3, b3, bufB);
            layer4f<<<dim3(tiles * 32), 256, 0, stream>>>(bufB, w4, b4, Amg, row0);
        }
    }

    // multigrid cascade: 16385 -> ... -> 524289; level 4 writes d_out (fp32).
    // mfma path: Amg holds raw layer-4 sums; relu(x+b4) applied at read.
    const float* b4p = use_mfma ? b4 : nullptr;
    const float* cur = Amg + 40;
    float* dsts[5] = {ahA, ahB, ahA, ahB, (float*)d_out};
    int n = 16385;
    for (int i = 0; i < 5; ++i) {
        int n_out = 2 * n - 1;
        mg_level<<<dim3((n_out + 255) / 256), 256, 0, stream>>>(
            cur, dsts[i], nbrs, i, Amg + 8 * (4 - i), n_out,
            b4p, (i == 0 && use_mfma) ? 1 : 0);
        cur = dsts[i];
        n = n_out;
    }
    (void)out_size;
}

// Round 9
// 893.825 us; speedup vs baseline: 1.4549x; 1.0232x over previous
//
#include <hip/hip_runtime.h>
#include <stdint.h>

#define HID    2048
#define MPTS   16425
#define MTILES 129    // ceil(16425/128)
#define NTIL   16     // 2048/128
#define KTIL   64     // 2048/32
#define BIMG   5120   // f16 elems per packed padded B tile image (128 rows * 40)

typedef float    f32x4 __attribute__((ext_vector_type(4)));
typedef _Float16 f16x8 __attribute__((ext_vector_type(8)));

// P-layout (A-operand fragment order) for activations:
// elem(row, k) -> linear ((tile*64+kt)<<12) + rowgrp*512 + quad*128 + lidx*8 + j
//   tile=row>>7, rowgrp=(row>>4)&7, lidx=row&15, kt=k>>5, quad=(k>>3)&3, j=k&7
// Consumer wave A-frag load = base + lane*8 halves (1KB fully coalesced).

// ---------------------------------------------------------------------------
// Pack fp32 W (K x N row-major) into single-fp16 padded tile images:
// img(L,nt,kt)[n*40+k] = (f16)W[kt*32+k][nt*128+n]; pad k=32..39 zeros.
// ---------------------------------------------------------------------------
__global__ void pack_w16(const float* __restrict__ w1,
                         const float* __restrict__ w2,
                         const float* __restrict__ w3,
                         _Float16* __restrict__ wp) {
    const int kt = blockIdx.x, nt = blockIdx.y, L = blockIdx.z;
    const float* W = (L == 0) ? w1 : ((L == 1) ? w2 : w3);
    __shared__ float tl[128 * 33];   // [n][k] transposed, padded
    const int tid = threadIdx.x;
    const int k  = tid >> 3;          // 0..31
    const int nc = (tid & 7) * 16;    // 0..112
    const float* src = W + (size_t)(kt * 32 + k) * HID + nt * 128 + nc;
    #pragma unroll
    for (int j = 0; j < 16; ++j) tl[(nc + j) * 33 + k] = src[j];
    __syncthreads();
    const size_t base = (size_t)(L * 1024 + nt * 64 + kt) * BIMG;
    for (int e = tid; e < BIMG; e += 256) {
        int n = e / 40, kk = e - n * 40;
        wp[base + e] = (kk < 32) ? (_Float16)tl[n * 33 + kk] : (_Float16)0.f;
    }
}

// ---------------------------------------------------------------------------
// MFMA GEMM v13 core (fp16), r8-proven: 32x128 wave tiles (unique A slice per
// wave -> minimal L2 A-traffic), distance-1 PF, partial-drain gate vmcnt(4),
// XCD-chunked bijective swizzle, optional fused layer-4 epilogue.
// ---------------------------------------------------------------------------
__launch_bounds__(256, 3)
__global__ void gemm_hl(const _Float16* __restrict__ Ahg,
                        const _Float16* __restrict__ Alg,
                        const _Float16* __restrict__ wp,
                        const float* __restrict__ bias,
                        _Float16* __restrict__ Chg,
                        _Float16* __restrict__ Clg,
                        int layer, int write_lo,
                        float* __restrict__ Amg4,
                        const float* __restrict__ w4g, int row0) {
    __shared__ _Float16 Bs[4][BIMG];   // 4 x 10240 B = 40 KB

    const int tid  = threadIdx.x;
    const int lane = tid & 63;
    const int wave = tid >> 6;
    const int quad = lane >> 4;
    const int lidx = lane & 15;

    const int nwg = (int)(gridDim.x * gridDim.y);
    const int L   = (int)(blockIdx.y * gridDim.x + blockIdx.x);
    const int F   = (L & 7) * (nwg >> 3) + (L >> 3);
    const int nt  = F & 15;
    const int mt  = F >> 4;

    const int mbase = wave * 32;        // each wave: 32 rows x 128 cols

    const char* gW = (const char*)(wp + (size_t)(layer * 1024 + nt * 64) * BIMG);

    const size_t abase = ((size_t)(mt * 64) << 12) + (size_t)(mbase >> 4) * 512 + (size_t)lane * 8;
    const _Float16* aH = Ahg + abase;
    const _Float16* aL = Alg + abase;

    f32x4 acc[2][8];
    #pragma unroll
    for (int i = 0; i < 2; ++i)
        #pragma unroll
        for (int j = 0; j < 8; ++j) acc[i][j] = (f32x4)0.f;

#define PF_B(KT, BUF) do {                                                            \
    const char* nW_ = gW + (size_t)(KT) * (BIMG * 2);                                 \
    char* dW_ = (char*)&Bs[BUF][0];                                                   \
    for (int t = wave; t < 10; t += 4) {                                              \
        __builtin_amdgcn_global_load_lds(                                             \
            (const __attribute__((address_space(1))) unsigned int*)(nW_ + t * 1024 + lane * 16), \
            (__attribute__((address_space(3))) unsigned int*)(dW_ + t * 1024), 16, 0, 0); \
    }                                                                                 \
} while (0)

#define LD_A(KT, H, Lo) do {                                                          \
    const size_t ak_ = (size_t)(KT) << 12;                                            \
    _Pragma("unroll")                                                                 \
    for (int mm = 0; mm < 2; ++mm) {                                                  \
        H[mm]  = *(const f16x8*)(aH + ak_ + mm * 512);                                \
        Lo[mm] = *(const f16x8*)(aL + ak_ + mm * 512);                                \
    }                                                                                 \
} while (0)

#define LD_B(BUF, BF) do {                                                            \
    _Pragma("unroll")                                                                 \
    for (int nn = 0; nn < 8; ++nn) {                                                  \
        int r_ = nn * 16 + lidx;                                                      \
        BF[nn] = *(const f16x8*)(&Bs[BUF][r_ * 40 + quad * 8]);                       \
    }                                                                                 \
} while (0)

#define MFMA32(AH, AL, BF) do {                                                       \
    _Pragma("unroll")                                                                 \
    for (int mm = 0; mm < 2; ++mm)                                                    \
        _Pragma("unroll")                                                             \
        for (int nn = 0; nn < 8; ++nn) {                                              \
            acc[mm][nn] = __builtin_amdgcn_mfma_f32_16x16x32_f16(AH[mm], BF[nn], acc[mm][nn], 0, 0, 0); \
            acc[mm][nn] = __builtin_amdgcn_mfma_f32_16x16x32_f16(AL[mm], BF[nn], acc[mm][nn], 0, 0, 0); \
        }                                                                             \
} while (0)

#define GATE4() do {                                                                  \
    asm volatile("s_waitcnt vmcnt(4)" ::: "memory");                                  \
    __builtin_amdgcn_sched_barrier(0);                                                \
    __builtin_amdgcn_s_barrier();                                                     \
    __builtin_amdgcn_sched_barrier(0);                                                \
} while (0)

#define SUPER(S, P, DO_PF, DO_A2) do {                                                \
    f16x8 bfr0_[8];                                                                   \
    LD_B(2 * (P), bfr0_);                                                             \
    if (DO_PF) { PF_B(2 * (S) + 2, 2 * ((P) ^ 1)); PF_B(2 * (S) + 3, 2 * ((P) ^ 1) + 1); } \
    LD_A(2 * (S) + 1, nah, nal);                                                      \
    MFMA32(cah, cal, bfr0_);                                                          \
    f16x8 bfr1_[8];                                                                   \
    LD_B(2 * (P) + 1, bfr1_);                                                         \
    if (DO_A2) LD_A(2 * (S) + 2, cah, cal);                                           \
    MFMA32(nah, nal, bfr1_);                                                          \
    GATE4();                                                                          \
} while (0)

    f16x8 cah[2], cal[2], nah[2], nal[2];

    PF_B(0, 0);
    PF_B(1, 1);
    LD_A(0, cah, cal);
    __syncthreads();

    for (int ss = 0; ss < 15; ++ss) {
        SUPER(2 * ss,     0, 1, 1);
        SUPER(2 * ss + 1, 1, 1, 1);
    }
    SUPER(30, 0, 1, 1);
    SUPER(31, 1, 0, 0);

#undef SUPER
#undef GATE4
#undef MFMA32
#undef LD_B
#undef LD_A
#undef PF_B

    if (Amg4) {
        // fused layer 4: h3 = relu(acc + b3); partial = h3 . w4 per row;
        // 16-lane reduce; one atomicAdd per row. relu(x+b4) applied in mg_level.
        float w4v[8], bv[8];
        #pragma unroll
        for (int nn = 0; nn < 8; ++nn) {
            const int col = nt * 128 + nn * 16 + lidx;
            w4v[nn] = w4g[col];
            bv[nn]  = bias[col];
        }
        #pragma unroll
        for (int mm = 0; mm < 2; ++mm) {
            #pragma unroll
            for (int r = 0; r < 4; ++r) {
                float p = 0.f;
                #pragma unroll
                for (int nn = 0; nn < 8; ++nn) {
                    float v = acc[mm][nn][r] + bv[nn];
                    v = v > 0.f ? v : 0.f;
                    p += v * w4v[nn];
                }
                #pragma unroll
                for (int off = 1; off <= 8; off <<= 1)
                    p += __shfl_xor(p, off, 16);
                if (lidx == 0) {
                    const int grow = row0 + mt * 128 + mbase + mm * 16 + quad * 4 + r;
                    if (grow < MPTS) atomicAdd(Amg4 + grow, p);
                }
            }
        }
        return;
    }

    // epilogue: C/D layout col=lane&15, row=quad*4+reg; write P-layout pair
    #pragma unroll
    for (int nn = 0; nn < 8; ++nn) {
        const int col = nt * 128 + nn * 16 + lidx;           // k of next layer
        const float bv = bias[col];
        const int kt2 = col >> 5, quad2 = (col >> 3) & 3, j2 = col & 7;
        const size_t cb = ((size_t)(mt * 64 + kt2) << 12) + quad2 * 128 + j2;
        #pragma unroll
        for (int mm = 0; mm < 2; ++mm) {
            const int rowg = (mbase >> 4) + mm;             // rowgrp
            #pragma unroll
            for (int r = 0; r < 4; ++r) {
                const int lidx2 = quad * 4 + r;             // row & 15
                float v = acc[mm][nn][r] + bv;
                v = v > 0.f ? v : 0.f;
                _Float16 hs = (_Float16)v;
                const size_t idx = cb + rowg * 512 + lidx2 * 8;
                Chg[idx] = hs;
                if (write_lo) Clg[idx] = (_Float16)(v - (float)hs);
            }
        }
    }
}

// ---------------------------------------------------------------------------
// MFMA GEMM v14 fused-L0 variant: A0 = relu(xs*w0+b0) is RANK-1 -- computed
// in-register instead of materialized. Per lane: 2 row-scalars xs (loaded
// once) + per-kt 8-float w0/b0 slices (4 vector loads = exactly the 4 A-loads
// they replace -> GATE4/vmcnt arithmetic identical to r8). COMP reproduces
// layer0p's arithmetic expression bit-for-bit (x*w0+b0, relu, cvt-hi,
// sub, cvt-lo). Removes layer0p dispatches + A0 HBM write/read + gemm-L0's
// 1.6 GB A-read L2 stream (the r8-proven mechanism).
// ---------------------------------------------------------------------------
__launch_bounds__(256, 3)
__global__ void gemm_f0(const float* __restrict__ xs,
                        const float* __restrict__ w0f,
                        const float* __restrict__ b0f,
                        const _Float16* __restrict__ wp,
                        const float* __restrict__ bias,
                        _Float16* __restrict__ Chg,
                        _Float16* __restrict__ Clg, int row0) {
    __shared__ _Float16 Bs[4][BIMG];   // 4 x 10240 B = 40 KB

    const int tid  = threadIdx.x;
    const int lane = tid & 63;
    const int wave = tid >> 6;
    const int quad = lane >> 4;
    const int lidx = lane & 15;

    const int nwg = (int)(gridDim.x * gridDim.y);
    const int L   = (int)(blockIdx.y * gridDim.x + blockIdx.x);
    const int F   = (L & 7) * (nwg >> 3) + (L >> 3);
    const int nt  = F & 15;
    const int mt  = F >> 4;

    const int mbase = wave * 32;

    const char* gW = (const char*)(wp + (size_t)(nt * 64) * BIMG);  // layer 0

    // per-lane row scalars (rows: mbase + mm*16 + lidx)
    const int g0 = row0 + mt * 128 + mbase + lidx;
    const float x0 = (g0 < MPTS) ? xs[g0] : 0.f;
    const float x1 = (g0 + 16 < MPTS) ? xs[g0 + 16] : 0.f;

    f32x4 acc[2][8];
    #pragma unroll
    for (int i = 0; i < 2; ++i)
        #pragma unroll
        for (int j = 0; j < 8; ++j) acc[i][j] = (f32x4)0.f;

#define PF0(KT, BUF) do {                                                             \
    const char* nW_ = gW + (size_t)(KT) * (BIMG * 2);                                 \
    char* dW_ = (char*)&Bs[BUF][0];                                                   \
    for (int t = wave; t < 10; t += 4) {                                              \
        __builtin_amdgcn_global_load_lds(                                             \
            (const __attribute__((address_space(1))) unsigned int*)(nW_ + t * 1024 + lane * 16), \
            (__attribute__((address_space(3))) unsigned int*)(dW_ + t * 1024), 16, 0, 0); \
    }                                                                                 \
} while (0)

// 4 vector loads of the w0/b0 slice for kt (replaces the 4 A-loads)
#define LDW0(KT, WA, WB, BA, BB) do {                                                 \
    const int k0_ = (KT) * 32 + quad * 8;                                             \
    WA = *(const f32x4*)(w0f + k0_);                                                  \
    WB = *(const f32x4*)(w0f + k0_ + 4);                                              \
    BA = *(const f32x4*)(b0f + k0_);                                                  \
    BB = *(const f32x4*)(b0f + k0_ + 4);                                              \
} while (0)

// build hi/lo A fragments: identical arithmetic to the old layer0p
#define COMP0(WA, WB, BA, BB) do {                                                    \
    _Pragma("unroll")                                                                 \
    for (int mm = 0; mm < 2; ++mm) {                                                  \
        const float xm_ = mm ? x1 : x0;                                               \
        f16x8 h_, l_;                                                                 \
        _Pragma("unroll")                                                             \
        for (int j = 0; j < 4; ++j) {                                                 \
            float v_ = xm_ * WA[j] + BA[j];                                           \
            v_ = v_ > 0.f ? v_ : 0.f;                                                 \
            _Float16 hs_ = (_Float16)v_;                                              \
            h_[j] = hs_; l_[j] = (_Float16)(v_ - (float)hs_);                         \
        }                                                                             \
        _Pragma("unroll")                                                             \
        for (int j = 0; j < 4; ++j) {                                                 \
            float v_ = xm_ * WB[j] + BB[j];                                           \
            v_ = v_ > 0.f ? v_ : 0.f;                                                 \
            _Float16 hs_ = (_Float16)v_;                                              \
            h_[4 + j] = hs_; l_[4 + j] = (_Float16)(v_ - (float)hs_);                 \
        }                                                                             \
        cah[mm] = h_; cal[mm] = l_;                                                   \
    }                                                                                 \
} while (0)

#define LDB0(BUF, BF) do {                                                            \
    _Pragma("unroll")                                                                 \
    for (int nn = 0; nn < 8; ++nn) {                                                  \
        int r_ = nn * 16 + lidx;                                                      \
        BF[nn] = *(const f16x8*)(&Bs[BUF][r_ * 40 + quad * 8]);                       \
    }                                                                                 \
} while (0)

#define MFMA0(BF) do {                                                                \
    _Pragma("unroll")                                                                 \
    for (int mm = 0; mm < 2; ++mm)                                                    \
        _Pragma("unroll")                                                             \
        for (int nn = 0; nn < 8; ++nn) {                                              \
            acc[mm][nn] = __builtin_amdgcn_mfma_f32_16x16x32_f16(cah[mm], BF[nn], acc[mm][nn], 0, 0, 0); \
            acc[mm][nn] = __builtin_amdgcn_mfma_f32_16x16x32_f16(cal[mm], BF[nn], acc[mm][nn], 0, 0, 0); \
        }                                                                             \
} while (0)

#define GATE0() do {                                                                  \
    asm volatile("s_waitcnt vmcnt(4)" ::: "memory");                                  \
    __builtin_amdgcn_sched_barrier(0);                                                \
    __builtin_amdgcn_s_barrier();                                                     \
    __builtin_amdgcn_sched_barrier(0);                                                \
} while (0)

// SUPERF(s): W(2s) in A-set (landed), buffers pair P hold images 2s,2s+1.
#define SUPERF(S, P, DO_PF, DO_W2) do {                                               \
    f16x8 bfr0_[8];                                                                   \
    LDB0(2 * (P), bfr0_);                                                             \
    if (DO_PF) { PF0(2 * (S) + 2, 2 * ((P) ^ 1)); PF0(2 * (S) + 3, 2 * ((P) ^ 1) + 1); } \
    LDW0(2 * (S) + 1, wBa, wBb, bBa, bBb);                                            \
    COMP0(wAa, wAb, bAa, bAb);          /* A(2s) */                                   \
    MFMA0(bfr0_);                                                                     \
    f16x8 bfr1_[8];                                                                   \
    LDB0(2 * (P) + 1, bfr1_);                                                         \
    if (DO_W2) LDW0(2 * (S) + 2, wAa, wAb, bAa, bAb);                                 \
    COMP0(wBa, wBb, bBa, bBb);          /* A(2s+1), loads landed during cluster1 */   \
    MFMA0(bfr1_);                                                                     \
    GATE0();                            /* drains PFs; keeps W(2s+2) in flight */     \
} while (0)

    f16x8 cah[2], cal[2];
    f32x4 wAa, wAb, bAa, bAb, wBa, wBb, bBa, bBb;

    PF0(0, 0);
    PF0(1, 1);
    LDW0(0, wAa, wAb, bAa, bAb);
    __syncthreads();

    for (int ss = 0; ss < 15; ++ss) {
        SUPERF(2 * ss,     0, 1, 1);
        SUPERF(2 * ss + 1, 1, 1, 1);
    }
    SUPERF(30, 0, 1, 1);
    SUPERF(31, 1, 0, 0);

#undef SUPERF
#undef GATE0
#undef MFMA0
#undef LDB0
#undef COMP0
#undef LDW0
#undef PF0

    // epilogue: write h1 hi/lo pair in P-layout (same as gemm_hl, write_lo=1)
    #pragma unroll
    for (int nn = 0; nn < 8; ++nn) {
        const int col = nt * 128 + nn * 16 + lidx;
        const float bv = bias[col];
        const int kt2 = col >> 5, quad2 = (col >> 3) & 3, j2 = col & 7;
        const size_t cb = ((size_t)(mt * 64 + kt2) << 12) + quad2 * 128 + j2;
        #pragma unroll
        for (int mm = 0; mm < 2; ++mm) {
            const int rowg = (mbase >> 4) + mm;
            #pragma unroll
            for (int r = 0; r < 4; ++r) {
                const int lidx2 = quad * 4 + r;
                float v = acc[mm][nn][r] + bv;
                v = v > 0.f ? v : 0.f;
                _Float16 hs = (_Float16)v;
                const size_t idx = cb + rowg * 512 + lidx2 * 8;
                Chg[idx] = hs;
                Clg[idx] = (_Float16)(v - (float)hs);
            }
        }
    }
}

// ---------------------------------------------------------------------------
// Fallback fp32 path (ws too small for packed images)
// ---------------------------------------------------------------------------
__global__ void layer0f(const float* __restrict__ xs, const float* __restrict__ w0,
                        const float* __restrict__ b0, float* __restrict__ A, int row0) {
    const int r = blockIdx.x;
    const int j = threadIdx.x * 8;
    const float x = (row0 + r < MPTS) ? xs[row0 + r] : 0.f;
    float* out = A + (size_t)r * HID + j;
    #pragma unroll
    for (int q = 0; q < 8; ++q) {
        float v = x * w0[j + q] + b0[j + q];
        out[q] = v > 0.f ? v : 0.f;
    }
}

__launch_bounds__(256)
__global__ void gemm_valu(const float* __restrict__ A, const float* __restrict__ W,
                          const float* __restrict__ bias, float* __restrict__ C) {
    __shared__ float As[16][132];
    __shared__ float Ws[16][132];
    const int tid = threadIdx.x;
    const int tx = tid & 15, ty = tid >> 4;
    const int n0 = blockIdx.x * 128;
    const int m0 = blockIdx.y * 128;
    const int am = tid & 127, ak = (tid >> 7) * 8;
    const int wn = (tid & 15) * 8, wk = tid >> 4;
    const float* aptr = A + (size_t)(m0 + am) * HID + ak;
    const float* wptr = W + (size_t)wk * HID + n0 + wn;
    float acc[8][8];
    #pragma unroll
    for (int i = 0; i < 8; ++i)
        #pragma unroll
        for (int j = 0; j < 8; ++j) acc[i][j] = 0.f;
    for (int k0 = 0; k0 < HID; k0 += 16) {
        f32x4 a0 = *(const f32x4*)(aptr + k0);
        f32x4 a1 = *(const f32x4*)(aptr + k0 + 4);
        f32x4 w0v = *(const f32x4*)(wptr + (size_t)k0 * HID);
        f32x4 w1v = *(const f32x4*)(wptr + (size_t)k0 * HID + 4);
        __syncthreads();
        As[ak + 0][am] = a0[0]; As[ak + 1][am] = a0[1];
        As[ak + 2][am] = a0[2]; As[ak + 3][am] = a0[3];
        As[ak + 4][am] = a1[0]; As[ak + 5][am] = a1[1];
        As[ak + 6][am] = a1[2]; As[ak + 7][am] = a1[3];
        *(f32x4*)&Ws[wk][wn]     = w0v;
        *(f32x4*)&Ws[wk][wn + 4] = w1v;
        __syncthreads();
        #pragma unroll
        for (int kk = 0; kk < 16; ++kk) {
            f32x4 av0 = *(const f32x4*)&As[kk][ty * 8];
            f32x4 av1 = *(const f32x4*)&As[kk][ty * 8 + 4];
            f32x4 bv0 = *(const f32x4*)&Ws[kk][tx * 8];
            f32x4 bv1 = *(const f32x4*)&Ws[kk][tx * 8 + 4];
            float a[8] = {av0[0], av0[1], av0[2], av0[3], av1[0], av1[1], av1[2], av1[3]};
            float b[8] = {bv0[0], bv0[1], bv0[2], bv0[3], bv1[0], bv1[1], bv1[2], bv1[3]};
            #pragma unroll
            for (int i = 0; i < 8; ++i)
                #pragma unroll
                for (int j = 0; j < 8; ++j) acc[i][j] += a[i] * b[j];
        }
    }
    #pragma unroll
    for (int i = 0; i < 8; ++i) {
        const int m = m0 + ty * 8 + i;
        #pragma unroll
        for (int jc = 0; jc < 2; ++jc) {
            const int n = n0 + tx * 8 + jc * 4;
            f32x4 v4;
            #pragma unroll
            for (int q = 0; q < 4; ++q) {
                float v = acc[i][jc * 4 + q] + bias[n + q];
                v4[q] = v > 0.f ? v : 0.f;
            }
            *(f32x4*)(C + (size_t)m * HID + n) = v4;
        }
    }
}

__global__ void layer4f(const float* __restrict__ A, const float* __restrict__ w4,
                        const float* __restrict__ b4, float* __restrict__ Amg, int row0) {
    const int lane = threadIdx.x & 63;
    const int wave = threadIdx.x >> 6;
    const int r    = blockIdx.x * 4 + wave;
    if (row0 + r >= MPTS) return;
    const float* ap = A + (size_t)r * HID;
    float s = 0.f;
    #pragma unroll
    for (int c = 0; c < 8; ++c) {
        const int col = c * 256 + lane * 4;
        f32x4 av = *(const f32x4*)(ap + col);
        f32x4 wv = *(const f32x4*)(w4 + col);
        s += av[0] * wv[0] + av[1] * wv[1] + av[2] * wv[2] + av[3] * wv[3];
    }
    #pragma unroll
    for (int off = 32; off; off >>= 1) s += __shfl_down(s, off);
    if (lane == 0) {
        float v = s + b4[0];
        Amg[row0 + r] = v > 0.f ? v : 0.f;
    }
}

// ---------------------------------------------------------------------------
// Multigrid level: interp (2n-1) + band overwrite; all fp32 (d_out is fp32).
// b4p non-null: apply f(x)=relu(x+b4) to band reads; xin: apply f to in[]
// (level 0 only, where in[] comes straight from raw Amg sums).
// ---------------------------------------------------------------------------
__global__ void mg_level(const float* __restrict__ in, float* __restrict__ outf,
                         const int* __restrict__ nbrs_base, int level,
                         const float* __restrict__ band, int n_out,
                         const float* __restrict__ b4p, int xin) {
    const int j = blockIdx.x * 256 + threadIdx.x;
    if (j >= n_out) return;
    const float b4v = b4p ? b4p[0] : 0.f;
    float v;
    if (j & 1) {
        float a = in[j >> 1], b = in[(j >> 1) + 1];
        if (xin) { a = fmaxf(a + b4v, 0.f); b = fmaxf(b + b4v, 0.f); }
        v = 0.5f * (a + b);
    } else {
        float a = in[j >> 1];
        if (xin) a = fmaxf(a + b4v, 0.f);
        v = a;
    }
    const int stride =
        (nbrs_base[1] == 0 && nbrs_base[3] == 0 && nbrs_base[5] == 0) ? 2 : 1;
    #pragma unroll
    for (int t = 0; t < 8; ++t) {
        const int idx = nbrs_base[(level * 8 + t) * stride];
        if (j == idx) {
            float bb = band[t];
            if (b4p) bb = fmaxf(bb + b4v, 0.f);
            v = bb;
        }
    }
    outf[j] = v;
}

// ---------------------------------------------------------------------------
extern "C" void kernel_launch(void* const* d_in, const int* in_sizes, int n_in,
                              void* d_out, int out_size, void* d_ws, size_t ws_size,
                              hipStream_t stream) {
    // ---- input order detection: dict (documented) / signature / alphabetical
    int iXS=0, iNB=1, iW0=4, iB0=5, iW1=6, iB1=7, iW2=8, iB2=9,
        iW3=10, iB3=11, iW4=12, iB4=13;                       // dict default
    if (n_in >= 14) {
        if (in_sizes[0] == HID) {
            iB0=0; iB1=1; iB2=2; iB3=3; iB4=4; iNB=7;
            iW0=8; iW1=9; iW2=10; iW3=11; iW4=12; iXS=13;
        } else if (!(in_sizes[1] == 40 || in_sizes[1] == 80)) {
            iXS=0; iW0=1; iB0=2; iW1=3; iB1=4; iW2=5; iB2=6;
            iW3=7; iB3=8; iW4=9; iB4=10; iNB=11;
        }
    }
    const float* xs = (const float*)d_in[iXS];
    const int* nbrs = (const int*)d_in[iNB];
    const float* w0 = (const float*)d_in[iW0];
    const float* b0 = (const float*)d_in[iB0];
    const float* w1 = (const float*)d_in[iW1];
    const float* b1 = (const float*)d_in[iB1];
    const float* w2 = (const float*)d_in[iW2];
    const float* b2 = (const float*)d_in[iB2];
    const float* w3 = (const float*)d_in[iW3];
    const float* b3 = (const float*)d_in[iB3];
    const float* w4 = (const float*)d_in[iW4];
    const float* b4 = (const float*)d_in[iB4];

    // ---- workspace layout ----
    char* ws = (char*)d_ws;
    const size_t szAmg = 66048;
    const size_t szAh1 = 524544;
    const size_t szAh2 = 1048832;
    float* Amg = (float*)(ws);
    float* ahA = (float*)(ws + szAmg);
    float* ahB = (float*)(ws + szAmg + szAh1);
    const size_t casc_end = szAmg + szAh1 + szAh2;       // 1,639,424
    const size_t szW    = (size_t)3 * 1024 * BIMG * 2;   // 31,457,280 (fp16)
    const size_t per_tile = 2ull * 128 * HID * 4;        // 2 MB (4 fp16 act bufs)

    const int use_mfma = (ws_size >= casc_end + szW + per_tile) ? 1 : 0;

    _Float16* wp = (_Float16*)(ws + casc_end);
    const size_t buf_start = use_mfma ? (casc_end + szW) : casc_end;

    size_t avail = ws_size - buf_start;
    int CT = (int)(avail / per_tile);
    if (CT < 1) CT = 1;
    if (CT > MTILES) CT = MTILES;   // single chunk when workspace allows

    if (use_mfma) {
        const size_t half = (size_t)CT * 128 * HID;       // f16 elems per buffer
        _Float16* bAh = (_Float16*)(ws + buf_start);
        _Float16* bAl = bAh + half;
        _Float16* bBh = bAh + 2 * half;
        _Float16* bBl = bAh + 3 * half;

        // fused layer-4 accumulates into Amg -> zero it (stream-ordered).
        hipMemsetAsync(Amg, 0, (size_t)MPTS * sizeof(float), stream);

        pack_w16<<<dim3(KTIL, NTIL, 3), 256, 0, stream>>>(w1, w2, w3, wp);

        for (int t0 = 0; t0 < MTILES; t0 += CT) {
            int tiles = (MTILES - t0 < CT) ? (MTILES - t0) : CT;
            int row0 = t0 * 128;
            dim3 ggrid(NTIL, tiles);
            // layer 0 fused with the xs->A0 rank-1 expansion (no layer0p)
            gemm_f0<<<ggrid, 256, 0, stream>>>(xs, w0, b0, wp, b1, bBh, bBl, row0);
            gemm_hl<<<ggrid, 256, 0, stream>>>(bBh, bBl, wp, b2, bAh, bAl, 1, 1,
                                               nullptr, nullptr, 0);
            // layer 2->3 gemm with fused layer-4 dot (no C write, no layer4p)
            gemm_hl<<<ggrid, 256, 0, stream>>>(bAh, bAl, wp, b3, bBh, bBl, 2, 0,
                                               Amg, w4, row0);
        }
    } else {
        float* bufA = (float*)(ws + buf_start);
        float* bufB = (float*)(ws + buf_start + (size_t)CT * 128 * HID * 4);
        for (int t0 = 0; t0 < MTILES; t0 += CT) {
            int tiles = (MTILES - t0 < CT) ? (MTILES - t0) : CT;
            int row0 = t0 * 128;
            layer0f<<<dim3(tiles * 128), 256, 0, stream>>>(xs, w0, b0, bufA, row0);
            dim3 ggrid(NTIL, tiles);
            gemm_valu<<<ggrid, 256, 0, stream>>>(bufA, w1, b1, bufB);
            gemm_valu<<<ggrid, 256, 0, stream>>>(bufB, w2, b2, bufA);
            gemm_valu<<<ggrid, 256, 0, stream>>>(bufA, w3, b3, bufB);
            layer4f<<<dim3(tiles * 32), 256, 0, stream>>>(bufB, w4, b4, Amg, row0);
        }
    }

    // multigrid cascade: 16385 -> ... -> 524289; level 4 writes d_out (fp32).
    // mfma path: Amg holds raw layer-4 sums; relu(x+b4) applied at read.
    const float* b4p = use_mfma ? b4 : nullptr;
    const float* cur = Amg + 40;
    float* dsts[5] = {ahA, ahB, ahA, ahB, (float*)d_out};
    int n = 16385;
    for (int i = 0; i < 5; ++i) {
        int n_out = 2 * n - 1;
        mg_level<<<dim3((n_out + 255) / 256), 256, 0, stream>>>(
            cur, dsts[i], nbrs, i, Amg + 8 * (4 - i), n_out,
            b4p, (i == 0 && use_mfma) ? 1 : 0);
        cur = dsts[i];
        n = n_out;
    }
    (void)out_size;
}

// Round 10
// 874.752 us; speedup vs baseline: 1.4867x; 1.0218x over previous
//
#include <hip/hip_runtime.h>
#include <stdint.h>

#define HID    2048
#define MPTS   16425
#define MTILES 129    // ceil(16425/128)
#define NTIL   16     // 2048/128
#define KTIL   64     // 2048/32
#define BIMG   5120   // f16 elems per packed padded B tile image (128 rows * 40)

typedef float    f32x4 __attribute__((ext_vector_type(4)));
typedef _Float16 f16x8 __attribute__((ext_vector_type(8)));

// P-layout (A-operand fragment order) for activations:
// elem(row, k) -> linear ((tile*64+kt)<<12) + rowgrp*512 + quad*128 + lidx*8 + j
//   tile=row>>7, rowgrp=(row>>4)&7, lidx=row&15, kt=k>>5, quad=(k>>3)&3, j=k&7
// Consumer wave A-frag load = base + lane*8 halves (1KB fully coalesced).

// ---------------------------------------------------------------------------
// Pack fp32 W (K x N row-major) into single-fp16 padded tile images:
// img(L,nt,kt)[n*40+k] = (f16)W[kt*32+k][nt*128+n]; pad k=32..39 zeros.
// ---------------------------------------------------------------------------
__global__ void pack_w16(const float* __restrict__ w1,
                         const float* __restrict__ w2,
                         const float* __restrict__ w3,
                         _Float16* __restrict__ wp) {
    const int kt = blockIdx.x, nt = blockIdx.y, L = blockIdx.z;
    const float* W = (L == 0) ? w1 : ((L == 1) ? w2 : w3);
    __shared__ float tl[128 * 33];   // [n][k] transposed, padded
    const int tid = threadIdx.x;
    const int k  = tid >> 3;          // 0..31
    const int nc = (tid & 7) * 16;    // 0..112
    const float* src = W + (size_t)(kt * 32 + k) * HID + nt * 128 + nc;
    #pragma unroll
    for (int j = 0; j < 16; ++j) tl[(nc + j) * 33 + k] = src[j];
    __syncthreads();
    const size_t base = (size_t)(L * 1024 + nt * 64 + kt) * BIMG;
    for (int e = tid; e < BIMG; e += 256) {
        int n = e / 40, kk = e - n * 40;
        wp[base + e] = (kk < 32) ? (_Float16)tl[n * 33 + kk] : (_Float16)0.f;
    }
}

// ---------------------------------------------------------------------------
// MFMA GEMM v13 core (fp16), r8-proven: 32x128 wave tiles (unique A slice per
// wave -> minimal L2 A-traffic), distance-1 PF, partial-drain gate vmcnt(4),
// XCD-chunked bijective swizzle, optional fused layer-4 epilogue. FROZEN.
// ---------------------------------------------------------------------------
__launch_bounds__(256, 3)
__global__ void gemm_hl(const _Float16* __restrict__ Ahg,
                        const _Float16* __restrict__ Alg,
                        const _Float16* __restrict__ wp,
                        const float* __restrict__ bias,
                        _Float16* __restrict__ Chg,
                        _Float16* __restrict__ Clg,
                        int layer, int write_lo,
                        float* __restrict__ Amg4,
                        const float* __restrict__ w4g, int row0) {
    __shared__ _Float16 Bs[4][BIMG];   // 4 x 10240 B = 40 KB

    const int tid  = threadIdx.x;
    const int lane = tid & 63;
    const int wave = tid >> 6;
    const int quad = lane >> 4;
    const int lidx = lane & 15;

    const int nwg = (int)(gridDim.x * gridDim.y);
    const int L   = (int)(blockIdx.y * gridDim.x + blockIdx.x);
    const int F   = (L & 7) * (nwg >> 3) + (L >> 3);
    const int nt  = F & 15;
    const int mt  = F >> 4;

    const int mbase = wave * 32;        // each wave: 32 rows x 128 cols

    const char* gW = (const char*)(wp + (size_t)(layer * 1024 + nt * 64) * BIMG);

    const size_t abase = ((size_t)(mt * 64) << 12) + (size_t)(mbase >> 4) * 512 + (size_t)lane * 8;
    const _Float16* aH = Ahg + abase;
    const _Float16* aL = Alg + abase;

    f32x4 acc[2][8];
    #pragma unroll
    for (int i = 0; i < 2; ++i)
        #pragma unroll
        for (int j = 0; j < 8; ++j) acc[i][j] = (f32x4)0.f;

#define PF_B(KT, BUF) do {                                                            \
    const char* nW_ = gW + (size_t)(KT) * (BIMG * 2);                                 \
    char* dW_ = (char*)&Bs[BUF][0];                                                   \
    for (int t = wave; t < 10; t += 4) {                                              \
        __builtin_amdgcn_global_load_lds(                                             \
            (const __attribute__((address_space(1))) unsigned int*)(nW_ + t * 1024 + lane * 16), \
            (__attribute__((address_space(3))) unsigned int*)(dW_ + t * 1024), 16, 0, 0); \
    }                                                                                 \
} while (0)

#define LD_A(KT, H, Lo) do {                                                          \
    const size_t ak_ = (size_t)(KT) << 12;                                            \
    _Pragma("unroll")                                                                 \
    for (int mm = 0; mm < 2; ++mm) {                                                  \
        H[mm]  = *(const f16x8*)(aH + ak_ + mm * 512);                                \
        Lo[mm] = *(const f16x8*)(aL + ak_ + mm * 512);                                \
    }                                                                                 \
} while (0)

#define LD_B(BUF, BF) do {                                                            \
    _Pragma("unroll")                                                                 \
    for (int nn = 0; nn < 8; ++nn) {                                                  \
        int r_ = nn * 16 + lidx;                                                      \
        BF[nn] = *(const f16x8*)(&Bs[BUF][r_ * 40 + quad * 8]);                       \
    }                                                                                 \
} while (0)

#define MFMA32(AH, AL, BF) do {                                                       \
    _Pragma("unroll")                                                                 \
    for (int mm = 0; mm < 2; ++mm)                                                    \
        _Pragma("unroll")                                                             \
        for (int nn = 0; nn < 8; ++nn) {                                              \
            acc[mm][nn] = __builtin_amdgcn_mfma_f32_16x16x32_f16(AH[mm], BF[nn], acc[mm][nn], 0, 0, 0); \
            acc[mm][nn] = __builtin_amdgcn_mfma_f32_16x16x32_f16(AL[mm], BF[nn], acc[mm][nn], 0, 0, 0); \
        }                                                                             \
} while (0)

#define GATE4() do {                                                                  \
    asm volatile("s_waitcnt vmcnt(4)" ::: "memory");                                  \
    __builtin_amdgcn_sched_barrier(0);                                                \
    __builtin_amdgcn_s_barrier();                                                     \
    __builtin_amdgcn_sched_barrier(0);                                                \
} while (0)

#define SUPER(S, P, DO_PF, DO_A2) do {                                                \
    f16x8 bfr0_[8];                                                                   \
    LD_B(2 * (P), bfr0_);                                                             \
    if (DO_PF) { PF_B(2 * (S) + 2, 2 * ((P) ^ 1)); PF_B(2 * (S) + 3, 2 * ((P) ^ 1) + 1); } \
    LD_A(2 * (S) + 1, nah, nal);                                                      \
    MFMA32(cah, cal, bfr0_);                                                          \
    f16x8 bfr1_[8];                                                                   \
    LD_B(2 * (P) + 1, bfr1_);                                                         \
    if (DO_A2) LD_A(2 * (S) + 2, cah, cal);                                           \
    MFMA32(nah, nal, bfr1_);                                                          \
    GATE4();                                                                          \
} while (0)

    f16x8 cah[2], cal[2], nah[2], nal[2];

    PF_B(0, 0);
    PF_B(1, 1);
    LD_A(0, cah, cal);
    __syncthreads();

    for (int ss = 0; ss < 15; ++ss) {
        SUPER(2 * ss,     0, 1, 1);
        SUPER(2 * ss + 1, 1, 1, 1);
    }
    SUPER(30, 0, 1, 1);
    SUPER(31, 1, 0, 0);

#undef SUPER
#undef GATE4
#undef MFMA32
#undef LD_B
#undef LD_A
#undef PF_B

    if (Amg4) {
        // fused layer 4: h3 = relu(acc + b3); partial = h3 . w4 per row;
        // 16-lane reduce; one atomicAdd per row. relu(x+b4) applied in mg_all.
        float w4v[8], bv[8];
        #pragma unroll
        for (int nn = 0; nn < 8; ++nn) {
            const int col = nt * 128 + nn * 16 + lidx;
            w4v[nn] = w4g[col];
            bv[nn]  = bias[col];
        }
        #pragma unroll
        for (int mm = 0; mm < 2; ++mm) {
            #pragma unroll
            for (int r = 0; r < 4; ++r) {
                float p = 0.f;
                #pragma unroll
                for (int nn = 0; nn < 8; ++nn) {
                    float v = acc[mm][nn][r] + bv[nn];
                    v = v > 0.f ? v : 0.f;
                    p += v * w4v[nn];
                }
                #pragma unroll
                for (int off = 1; off <= 8; off <<= 1)
                    p += __shfl_xor(p, off, 16);
                if (lidx == 0) {
                    const int grow = row0 + mt * 128 + mbase + mm * 16 + quad * 4 + r;
                    if (grow < MPTS) atomicAdd(Amg4 + grow, p);
                }
            }
        }
        return;
    }

    // epilogue: C/D layout col=lane&15, row=quad*4+reg; write P-layout pair
    #pragma unroll
    for (int nn = 0; nn < 8; ++nn) {
        const int col = nt * 128 + nn * 16 + lidx;           // k of next layer
        const float bv = bias[col];
        const int kt2 = col >> 5, quad2 = (col >> 3) & 3, j2 = col & 7;
        const size_t cb = ((size_t)(mt * 64 + kt2) << 12) + quad2 * 128 + j2;
        #pragma unroll
        for (int mm = 0; mm < 2; ++mm) {
            const int rowg = (mbase >> 4) + mm;             // rowgrp
            #pragma unroll
            for (int r = 0; r < 4; ++r) {
                const int lidx2 = quad * 4 + r;             // row & 15
                float v = acc[mm][nn][r] + bv;
                v = v > 0.f ? v : 0.f;
                _Float16 hs = (_Float16)v;
                const size_t idx = cb + rowg * 512 + lidx2 * 8;
                Chg[idx] = hs;
                if (write_lo) Clg[idx] = (_Float16)(v - (float)hs);
            }
        }
    }
}

// ---------------------------------------------------------------------------
// MFMA GEMM v14 fused-L0 variant (r9): A0 = relu(xs*w0+b0) is RANK-1,
// computed in-register. Net ~neutral vs layer0p+gemm at same grid, but
// removes A0 HBM write/read + layer0p dispatches. FROZEN.
// ---------------------------------------------------------------------------
__launch_bounds__(256, 3)
__global__ void gemm_f0(const float* __restrict__ xs,
                        const float* __restrict__ w0f,
                        const float* __restrict__ b0f,
                        const _Float16* __restrict__ wp,
                        const float* __restrict__ bias,
                        _Float16* __restrict__ Chg,
                        _Float16* __restrict__ Clg, int row0) {
    __shared__ _Float16 Bs[4][BIMG];   // 4 x 10240 B = 40 KB

    const int tid  = threadIdx.x;
    const int lane = tid & 63;
    const int wave = tid >> 6;
    const int quad = lane >> 4;
    const int lidx = lane & 15;

    const int nwg = (int)(gridDim.x * gridDim.y);
    const int L   = (int)(blockIdx.y * gridDim.x + blockIdx.x);
    const int F   = (L & 7) * (nwg >> 3) + (L >> 3);
    const int nt  = F & 15;
    const int mt  = F >> 4;

    const int mbase = wave * 32;

    const char* gW = (const char*)(wp + (size_t)(nt * 64) * BIMG);  // layer 0

    // per-lane row scalars (rows: mbase + mm*16 + lidx)
    const int g0 = row0 + mt * 128 + mbase + lidx;
    const float x0 = (g0 < MPTS) ? xs[g0] : 0.f;
    const float x1 = (g0 + 16 < MPTS) ? xs[g0 + 16] : 0.f;

    f32x4 acc[2][8];
    #pragma unroll
    for (int i = 0; i < 2; ++i)
        #pragma unroll
        for (int j = 0; j < 8; ++j) acc[i][j] = (f32x4)0.f;

#define PF0(KT, BUF) do {                                                             \
    const char* nW_ = gW + (size_t)(KT) * (BIMG * 2);                                 \
    char* dW_ = (char*)&Bs[BUF][0];                                                   \
    for (int t = wave; t < 10; t += 4) {                                              \
        __builtin_amdgcn_global_load_lds(                                             \
            (const __attribute__((address_space(1))) unsigned int*)(nW_ + t * 1024 + lane * 16), \
            (__attribute__((address_space(3))) unsigned int*)(dW_ + t * 1024), 16, 0, 0); \
    }                                                                                 \
} while (0)

#define LDW0(KT, WA, WB, BA, BB) do {                                                 \
    const int k0_ = (KT) * 32 + quad * 8;                                             \
    WA = *(const f32x4*)(w0f + k0_);                                                  \
    WB = *(const f32x4*)(w0f + k0_ + 4);                                              \
    BA = *(const f32x4*)(b0f + k0_);                                                  \
    BB = *(const f32x4*)(b0f + k0_ + 4);                                              \
} while (0)

#define COMP0(WA, WB, BA, BB) do {                                                    \
    _Pragma("unroll")                                                                 \
    for (int mm = 0; mm < 2; ++mm) {                                                  \
        const float xm_ = mm ? x1 : x0;                                               \
        f16x8 h_, l_;                                                                 \
        _Pragma("unroll")                                                             \
        for (int j = 0; j < 4; ++j) {                                                 \
            float v_ = xm_ * WA[j] + BA[j];                                           \
            v_ = v_ > 0.f ? v_ : 0.f;                                                 \
            _Float16 hs_ = (_Float16)v_;                                              \
            h_[j] = hs_; l_[j] = (_Float16)(v_ - (float)hs_);                         \
        }                                                                             \
        _Pragma("unroll")                                                             \
        for (int j = 0; j < 4; ++j) {                                                 \
            float v_ = xm_ * WB[j] + BB[j];                                           \
            v_ = v_ > 0.f ? v_ : 0.f;                                                 \
            _Float16 hs_ = (_Float16)v_;                                              \
            h_[4 + j] = hs_; l_[4 + j] = (_Float16)(v_ - (float)hs_);                 \
        }                                                                             \
        cah[mm] = h_; cal[mm] = l_;                                                   \
    }                                                                                 \
} while (0)

#define LDB0(BUF, BF) do {                                                            \
    _Pragma("unroll")                                                                 \
    for (int nn = 0; nn < 8; ++nn) {                                                  \
        int r_ = nn * 16 + lidx;                                                      \
        BF[nn] = *(const f16x8*)(&Bs[BUF][r_ * 40 + quad * 8]);                       \
    }                                                                                 \
} while (0)

#define MFMA0(BF) do {                                                                \
    _Pragma("unroll")                                                                 \
    for (int mm = 0; mm < 2; ++mm)                                                    \
        _Pragma("unroll")                                                             \
        for (int nn = 0; nn < 8; ++nn) {                                              \
            acc[mm][nn] = __builtin_amdgcn_mfma_f32_16x16x32_f16(cah[mm], BF[nn], acc[mm][nn], 0, 0, 0); \
            acc[mm][nn] = __builtin_amdgcn_mfma_f32_16x16x32_f16(cal[mm], BF[nn], acc[mm][nn], 0, 0, 0); \
        }                                                                             \
} while (0)

#define GATE0() do {                                                                  \
    asm volatile("s_waitcnt vmcnt(4)" ::: "memory");                                  \
    __builtin_amdgcn_sched_barrier(0);                                                \
    __builtin_amdgcn_s_barrier();                                                     \
    __builtin_amdgcn_sched_barrier(0);                                                \
} while (0)

#define SUPERF(S, P, DO_PF, DO_W2) do {                                               \
    f16x8 bfr0_[8];                                                                   \
    LDB0(2 * (P), bfr0_);                                                             \
    if (DO_PF) { PF0(2 * (S) + 2, 2 * ((P) ^ 1)); PF0(2 * (S) + 3, 2 * ((P) ^ 1) + 1); } \
    LDW0(2 * (S) + 1, wBa, wBb, bBa, bBb);                                            \
    COMP0(wAa, wAb, bAa, bAb);          /* A(2s) */                                   \
    MFMA0(bfr0_);                                                                     \
    f16x8 bfr1_[8];                                                                   \
    LDB0(2 * (P) + 1, bfr1_);                                                         \
    if (DO_W2) LDW0(2 * (S) + 2, wAa, wAb, bAa, bAb);                                 \
    COMP0(wBa, wBb, bBa, bBb);          /* A(2s+1) */                                 \
    MFMA0(bfr1_);                                                                     \
    GATE0();                                                                          \
} while (0)

    f16x8 cah[2], cal[2];
    f32x4 wAa, wAb, bAa, bAb, wBa, wBb, bBa, bBb;

    PF0(0, 0);
    PF0(1, 1);
    LDW0(0, wAa, wAb, bAa, bAb);
    __syncthreads();

    for (int ss = 0; ss < 15; ++ss) {
        SUPERF(2 * ss,     0, 1, 1);
        SUPERF(2 * ss + 1, 1, 1, 1);
    }
    SUPERF(30, 0, 1, 1);
    SUPERF(31, 1, 0, 0);

#undef SUPERF
#undef GATE0
#undef MFMA0
#undef LDB0
#undef COMP0
#undef LDW0
#undef PF0

    // epilogue: write h1 hi/lo pair in P-layout
    #pragma unroll
    for (int nn = 0; nn < 8; ++nn) {
        const int col = nt * 128 + nn * 16 + lidx;
        const float bv = bias[col];
        const int kt2 = col >> 5, quad2 = (col >> 3) & 3, j2 = col & 7;
        const size_t cb = ((size_t)(mt * 64 + kt2) << 12) + quad2 * 128 + j2;
        #pragma unroll
        for (int mm = 0; mm < 2; ++mm) {
            const int rowg = (mbase >> 4) + mm;
            #pragma unroll
            for (int r = 0; r < 4; ++r) {
                const int lidx2 = quad * 4 + r;
                float v = acc[mm][nn][r] + bv;
                v = v > 0.f ? v : 0.f;
                _Float16 hs = (_Float16)v;
                const size_t idx = cb + rowg * 512 + lidx2 * 8;
                Chg[idx] = hs;
                Clg[idx] = (_Float16)(v - (float)hs);
            }
        }
    }
}

// ---------------------------------------------------------------------------
// Fallback fp32 path (ws too small for packed images)
// ---------------------------------------------------------------------------
__global__ void layer0f(const float* __restrict__ xs, const float* __restrict__ w0,
                        const float* __restrict__ b0, float* __restrict__ A, int row0) {
    const int r = blockIdx.x;
    const int j = threadIdx.x * 8;
    const float x = (row0 + r < MPTS) ? xs[row0 + r] : 0.f;
    float* out = A + (size_t)r * HID + j;
    #pragma unroll
    for (int q = 0; q < 8; ++q) {
        float v = x * w0[j + q] + b0[j + q];
        out[q] = v > 0.f ? v : 0.f;
    }
}

__launch_bounds__(256)
__global__ void gemm_valu(const float* __restrict__ A, const float* __restrict__ W,
                          const float* __restrict__ bias, float* __restrict__ C) {
    __shared__ float As[16][132];
    __shared__ float Ws[16][132];
    const int tid = threadIdx.x;
    const int tx = tid & 15, ty = tid >> 4;
    const int n0 = blockIdx.x * 128;
    const int m0 = blockIdx.y * 128;
    const int am = tid & 127, ak = (tid >> 7) * 8;
    const int wn = (tid & 15) * 8, wk = tid >> 4;
    const float* aptr = A + (size_t)(m0 + am) * HID + ak;
    const float* wptr = W + (size_t)wk * HID + n0 + wn;
    float acc[8][8];
    #pragma unroll
    for (int i = 0; i < 8; ++i)
        #pragma unroll
        for (int j = 0; j < 8; ++j) acc[i][j] = 0.f;
    for (int k0 = 0; k0 < HID; k0 += 16) {
        f32x4 a0 = *(const f32x4*)(aptr + k0);
        f32x4 a1 = *(const f32x4*)(aptr + k0 + 4);
        f32x4 w0v = *(const f32x4*)(wptr + (size_t)k0 * HID);
        f32x4 w1v = *(const f32x4*)(wptr + (size_t)k0 * HID + 4);
        __syncthreads();
        As[ak + 0][am] = a0[0]; As[ak + 1][am] = a0[1];
        As[ak + 2][am] = a0[2]; As[ak + 3][am] = a0[3];
        As[ak + 4][am] = a1[0]; As[ak + 5][am] = a1[1];
        As[ak + 6][am] = a1[2]; As[ak + 7][am] = a1[3];
        *(f32x4*)&Ws[wk][wn]     = w0v;
        *(f32x4*)&Ws[wk][wn + 4] = w1v;
        __syncthreads();
        #pragma unroll
        for (int kk = 0; kk < 16; ++kk) {
            f32x4 av0 = *(const f32x4*)&As[kk][ty * 8];
            f32x4 av1 = *(const f32x4*)&As[kk][ty * 8 + 4];
            f32x4 bv0 = *(const f32x4*)&Ws[kk][tx * 8];
            f32x4 bv1 = *(const f32x4*)&Ws[kk][tx * 8 + 4];
            float a[8] = {av0[0], av0[1], av0[2], av0[3], av1[0], av1[1], av1[2], av1[3]};
            float b[8] = {bv0[0], bv0[1], bv0[2], bv0[3], bv1[0], bv1[1], bv1[2], bv1[3]};
            #pragma unroll
            for (int i = 0; i < 8; ++i)
                #pragma unroll
                for (int j = 0; j < 8; ++j) acc[i][j] += a[i] * b[j];
        }
    }
    #pragma unroll
    for (int i = 0; i < 8; ++i) {
        const int m = m0 + ty * 8 + i;
        #pragma unroll
        for (int jc = 0; jc < 2; ++jc) {
            const int n = n0 + tx * 8 + jc * 4;
            f32x4 v4;
            #pragma unroll
            for (int q = 0; q < 4; ++q) {
                float v = acc[i][jc * 4 + q] + bias[n + q];
                v4[q] = v > 0.f ? v : 0.f;
            }
            *(f32x4*)(C + (size_t)m * HID + n) = v4;
        }
    }
}

__global__ void layer4f(const float* __restrict__ A, const float* __restrict__ w4,
                        const float* __restrict__ b4, float* __restrict__ Amg, int row0) {
    const int lane = threadIdx.x & 63;
    const int wave = threadIdx.x >> 6;
    const int r    = blockIdx.x * 4 + wave;
    if (row0 + r >= MPTS) return;
    const float* ap = A + (size_t)r * HID;
    float s = 0.f;
    #pragma unroll
    for (int c = 0; c < 8; ++c) {
        const int col = c * 256 + lane * 4;
        f32x4 av = *(const f32x4*)(ap + col);
        f32x4 wv = *(const f32x4*)(w4 + col);
        s += av[0] * wv[0] + av[1] * wv[1] + av[2] * wv[2] + av[3] * wv[3];
    }
    #pragma unroll
    for (int off = 32; off; off >>= 1) s += __shfl_down(s, off);
    if (lane == 0) {
        float v = s + b4[0];
        Amg[row0 + r] = v > 0.f ? v : 0.f;
    }
}

// ---------------------------------------------------------------------------
// Fused multigrid cascade: all 5 levels in ONE kernel. Each block computes
// 256 final outputs by back-tracing its dependency cone (widths
// 256->130->67->35->19->11) and recomputing the local cascade in LDS.
// Identical per-element arithmetic/order to the old 5x mg_level chain
// (0.5*(a+b); f(x)=relu(x+b4) applied at the same read points) -> bitwise
// identical. b4p null => f = identity (fallback path).
// ---------------------------------------------------------------------------
__global__ void mg_all(const float* __restrict__ Amg, float* __restrict__ outf,
                       const int* __restrict__ nbrs, const float* __restrict__ b4p) {
    __shared__ float Lb[16], L0[24], L1[40], L2[72], L3[136];
    const int t = threadIdx.x;
    const int NFIN = 524289;
    const int o0 = (int)blockIdx.x * 256;
    const float b4v = b4p ? b4p[0] : 0.f;
    const int stride = (nbrs[1] == 0 && nbrs[3] == 0 && nbrs[5] == 0) ? 2 : 1;

#define MGF(x) (b4p ? fmaxf((x) + b4v, 0.f) : (x))

    // dependency-cone ranges (all threads compute identically)
    const int nin[5] = {16385, 32769, 65537, 131073, 262145};
    int OS4 = o0;
    int OC4 = (NFIN - o0 < 256) ? (NFIN - o0) : 256;
    int IS4 = (OS4 > 0) ? ((OS4 - 1) >> 1) : 0;
    int IE4 = ((OS4 + OC4) >> 1) + 1; if (IE4 > nin[4]) IE4 = nin[4];
    int OS3 = IS4, OC3 = IE4 - IS4;
    int IS3 = (OS3 > 0) ? ((OS3 - 1) >> 1) : 0;
    int IE3 = ((OS3 + OC3) >> 1) + 1; if (IE3 > nin[3]) IE3 = nin[3];
    int OS2 = IS3, OC2 = IE3 - IS3;
    int IS2 = (OS2 > 0) ? ((OS2 - 1) >> 1) : 0;
    int IE2 = ((OS2 + OC2) >> 1) + 1; if (IE2 > nin[2]) IE2 = nin[2];
    int OS1 = IS2, OC1 = IE2 - IS2;
    int IS1 = (OS1 > 0) ? ((OS1 - 1) >> 1) : 0;
    int IE1 = ((OS1 + OC1) >> 1) + 1; if (IE1 > nin[1]) IE1 = nin[1];
    int OS0 = IS1, OC0 = IE1 - IS1;
    int IS0 = (OS0 > 0) ? ((OS0 - 1) >> 1) : 0;
    int IE0 = ((OS0 + OC0) >> 1) + 1; if (IE0 > nin[0]) IE0 = nin[0];
    int BS = IS0, BC = IE0 - IS0;

    // base: Ah = f(Amg[40 + .])
    if (t < BC) Lb[t] = MGF(Amg[40 + BS + t]);
    __syncthreads();

#define MG_STAGE(LVL, INARR, INS, OUTARR, OS_, OC_) do {                              \
    if (t < (OC_)) {                                                                  \
        const int gj = (OS_) + t;                                                     \
        const int h = gj >> 1;                                                        \
        float v;                                                                      \
        if (gj & 1) v = 0.5f * (INARR[h - (INS)] + INARR[h + 1 - (INS)]);             \
        else        v = INARR[h - (INS)];                                             \
        _Pragma("unroll")                                                             \
        for (int t8 = 0; t8 < 8; ++t8) {                                              \
            const int idx = nbrs[((LVL) * 8 + t8) * stride];                          \
            if (idx == gj) v = MGF(Amg[8 * (4 - (LVL)) + t8]);                        \
        }                                                                             \
        OUTARR[t] = v;                                                                \
    }                                                                                 \
    __syncthreads();                                                                  \
} while (0)

    MG_STAGE(0, Lb, BS,  L0, OS0, OC0);
    MG_STAGE(1, L0, OS0, L1, OS1, OC1);
    MG_STAGE(2, L1, OS1, L2, OS2, OC2);
    MG_STAGE(3, L2, OS2, L3, OS3, OC3);

    // final level writes straight to global
    if (t < OC4) {
        const int gj = OS4 + t;
        const int h = gj >> 1;
        float v;
        if (gj & 1) v = 0.5f * (L3[h - OS3] + L3[h + 1 - OS3]);
        else        v = L3[h - OS3];
        #pragma unroll
        for (int t8 = 0; t8 < 8; ++t8) {
            const int idx = nbrs[(4 * 8 + t8) * stride];
            if (idx == gj) v = MGF(Amg[t8]);
        }
        outf[gj] = v;
    }

#undef MG_STAGE
#undef MGF
}

// ---------------------------------------------------------------------------
extern "C" void kernel_launch(void* const* d_in, const int* in_sizes, int n_in,
                              void* d_out, int out_size, void* d_ws, size_t ws_size,
                              hipStream_t stream) {
    // ---- input order detection: dict (documented) / signature / alphabetical
    int iXS=0, iNB=1, iW0=4, iB0=5, iW1=6, iB1=7, iW2=8, iB2=9,
        iW3=10, iB3=11, iW4=12, iB4=13;                       // dict default
    if (n_in >= 14) {
        if (in_sizes[0] == HID) {
            iB0=0; iB1=1; iB2=2; iB3=3; iB4=4; iNB=7;
            iW0=8; iW1=9; iW2=10; iW3=11; iW4=12; iXS=13;
        } else if (!(in_sizes[1] == 40 || in_sizes[1] == 80)) {
            iXS=0; iW0=1; iB0=2; iW1=3; iB1=4; iW2=5; iB2=6;
            iW3=7; iB3=8; iW4=9; iB4=10; iNB=11;
        }
    }
    const float* xs = (const float*)d_in[iXS];
    const int* nbrs = (const int*)d_in[iNB];
    const float* w0 = (const float*)d_in[iW0];
    const float* b0 = (const float*)d_in[iB0];
    const float* w1 = (const float*)d_in[iW1];
    const float* b1 = (const float*)d_in[iB1];
    const float* w2 = (const float*)d_in[iW2];
    const float* b2 = (const float*)d_in[iB2];
    const float* w3 = (const float*)d_in[iW3];
    const float* b3 = (const float*)d_in[iB3];
    const float* w4 = (const float*)d_in[iW4];
    const float* b4 = (const float*)d_in[iB4];

    // ---- workspace layout ----
    char* ws = (char*)d_ws;
    const size_t szAmg = 66048;
    const size_t szAh1 = 524544;
    const size_t szAh2 = 1048832;
    float* Amg = (float*)(ws);
    float* ahA = (float*)(ws + szAmg);
    float* ahB = (float*)(ws + szAmg + szAh1);
    const size_t casc_end = szAmg + szAh1 + szAh2;       // 1,639,424
    const size_t szW    = (size_t)3 * 1024 * BIMG * 2;   // 31,457,280 (fp16)
    const size_t per_tile = 2ull * 128 * HID * 4;        // 2 MB (4 fp16 act bufs)

    const int use_mfma = (ws_size >= casc_end + szW + per_tile) ? 1 : 0;

    _Float16* wp = (_Float16*)(ws + casc_end);
    const size_t buf_start = use_mfma ? (casc_end + szW) : casc_end;

    size_t avail = ws_size - buf_start;
    int CT = (int)(avail / per_tile);
    if (CT < 1) CT = 1;
    if (CT > MTILES) CT = MTILES;   // single chunk when workspace allows

    if (use_mfma) {
        const size_t half = (size_t)CT * 128 * HID;       // f16 elems per buffer
        _Float16* bAh = (_Float16*)(ws + buf_start);
        _Float16* bAl = bAh + half;
        _Float16* bBh = bAh + 2 * half;
        _Float16* bBl = bAh + 3 * half;

        // fused layer-4 accumulates into Amg -> zero it (stream-ordered).
        hipMemsetAsync(Amg, 0, (size_t)MPTS * sizeof(float), stream);

        pack_w16<<<dim3(KTIL, NTIL, 3), 256, 0, stream>>>(w1, w2, w3, wp);

        for (int t0 = 0; t0 < MTILES; t0 += CT) {
            int tiles = (MTILES - t0 < CT) ? (MTILES - t0) : CT;
            int row0 = t0 * 128;
            dim3 ggrid(NTIL, tiles);
            // layer 0 fused with the xs->A0 rank-1 expansion (no layer0p)
            gemm_f0<<<ggrid, 256, 0, stream>>>(xs, w0, b0, wp, b1, bBh, bBl, row0);
            gemm_hl<<<ggrid, 256, 0, stream>>>(bBh, bBl, wp, b2, bAh, bAl, 1, 1,
                                               nullptr, nullptr, 0);
            // layer 2->3 gemm with fused layer-4 dot (no C write, no layer4p)
            gemm_hl<<<ggrid, 256, 0, stream>>>(bAh, bAl, wp, b3, bBh, bBl, 2, 0,
                                               Amg, w4, row0);
        }
    } else {
        float* bufA = (float*)(ws + buf_start);
        float* bufB = (float*)(ws + buf_start + (size_t)CT * 128 * HID * 4);
        for (int t0 = 0; t0 < MTILES; t0 += CT) {
            int tiles = (MTILES - t0 < CT) ? (MTILES - t0) : CT;
            int row0 = t0 * 128;
            layer0f<<<dim3(tiles * 128), 256, 0, stream>>>(xs, w0, b0, bufA, row0);
            dim3 ggrid(NTIL, tiles);
            gemm_valu<<<ggrid, 256, 0, stream>>>(bufA, w1, b1, bufB);
            gemm_valu<<<ggrid, 256, 0, stream>>>(bufB, w2, b2, bufA);
            gemm_valu<<<ggrid, 256, 0, stream>>>(bufA, w3, b3, bufB);
            layer4f<<<dim3(tiles * 32), 256, 0, stream>>>(bufB, w4, b4, Amg, row0);
        }
    }

    // fused multigrid cascade: one kernel for all 5 levels (final = 524289).
    // mfma path: Amg holds raw layer-4 sums; relu(x+b4) applied at read.
    const float* b4p = use_mfma ? b4 : nullptr;
    mg_all<<<dim3((524289 + 255) / 256), 256, 0, stream>>>(
        Amg, (float*)d_out, nbrs, b4p);
    (void)ahA; (void)ahB;
    (void)out_size;
}